// Round 12
// baseline (314.946 us; speedup 1.0000x reference)
//
#include <hip/hip_runtime.h>
#include <cstdint>
#include <cstddef>

#define NN 50000
#define NE 800000
#define RREL 5
#define NR (NN * RREL)                 // 250000 (dst,type) keys
#define NB5 ((NR + 255) / 256)         // 977

typedef __attribute__((ext_vector_type(8))) short short8;   // 8 bf16 (4 VGPRs)
typedef __attribute__((ext_vector_type(4))) float f32x4;

static __device__ __forceinline__ float lrelu(float v) { return v > 0.f ? v : 0.01f * v; }

static __device__ __forceinline__ unsigned short f32_bf16_rn(float x) {
    unsigned u = __float_as_uint(x);
    return (unsigned short)((u + 0x7FFFu + ((u >> 16) & 1u)) >> 16);
}

// split 8 f32 (two float4) into bf16 hi + lo (x ~= hi + lo)
static __device__ __forceinline__ void split8v(float4 q0, float4 q1, short8& hi, short8& lo) {
    float v[8] = {q0.x, q0.y, q0.z, q0.w, q1.x, q1.y, q1.z, q1.w};
    #pragma unroll
    for (int j = 0; j < 8; ++j) {
        unsigned short h = f32_bf16_rn(v[j]);
        float hf = __uint_as_float(((unsigned)h) << 16);
        unsigned short l = f32_bf16_rn(v[j] - hf);
        hi[j] = (short)h; lo[j] = (short)l;
    }
}

// ---------------------------------------------------------------------------
// 64x64-tile f32 GEMM (e0 = x @ field_W + field_b, K=128)
// ---------------------------------------------------------------------------
template<int K>
__launch_bounds__(256)
__global__ void gemm_tile(const float* __restrict__ A, int lda,
                          const float* __restrict__ B0,
                          const float* __restrict__ bias,
                          float* __restrict__ C, int M)
{
    __shared__ float As[64][68];
    __shared__ float Bs[64][64];
    const int row0 = blockIdx.x * 64;
    const int t = threadIdx.x;
    const int tx = t & 15, ty = t >> 4;

    float acc[4][4] = {};

    for (int kc = 0; kc < K; kc += 64) {
        {
            int arow = t >> 4, akk = (t & 15) << 2;
            #pragma unroll
            for (int rp = 0; rp < 64; rp += 16) {
                int r = rp + arow, gr = row0 + r;
                float4 v = make_float4(0.f, 0.f, 0.f, 0.f);
                if (gr < M) v = *(const float4*)&A[(size_t)gr * lda + kc + akk];
                As[akk + 0][r] = v.x; As[akk + 1][r] = v.y;
                As[akk + 2][r] = v.z; As[akk + 3][r] = v.w;
            }
        }
        #pragma unroll
        for (int idx = t; idx < 1024; idx += 256) {
            int k = idx >> 4, c4 = (idx & 15) << 2;
            *(float4*)&Bs[k][c4] = *(const float4*)&B0[(size_t)(kc + k) * 64 + c4];
        }
        __syncthreads();

        #pragma unroll 8
        for (int k = 0; k < 64; ++k) {
            float4 av = *(const float4*)&As[k][ty * 4];
            float4 bv = *(const float4*)&Bs[k][tx * 4];
            float ar[4] = {av.x, av.y, av.z, av.w};
            float br[4] = {bv.x, bv.y, bv.z, bv.w};
            #pragma unroll
            for (int i = 0; i < 4; ++i)
                #pragma unroll
                for (int j = 0; j < 4; ++j)
                    acc[i][j] = fmaf(ar[i], br[j], acc[i][j]);
        }
        __syncthreads();
    }

    float bb[4];
    {
        const float* bp = bias + tx * 4;
        bb[0] = bp[0]; bb[1] = bp[1]; bb[2] = bp[2]; bb[3] = bp[3];
    }
    #pragma unroll
    for (int i = 0; i < 4; ++i) {
        int gr = row0 + ty * 4 + i;
        if (gr >= M) continue;
        *(float4*)&C[(size_t)gr * 64 + tx * 4] =
            make_float4(acc[i][0] + bb[0], acc[i][1] + bb[1],
                        acc[i][2] + bb[2], acc[i][3] + bb[3]);
    }
}

// ---------------------------------------------------------------------------
// zgather v4: one wave per dst node, full-range 8-deep pipelined walk with
// wave-uniform segment flushes. Nontemporal Z/S stores (no write-allocate,
// no L2 pollution); epack loaded as nontemporal u64 (streamed once).
// ---------------------------------------------------------------------------
__launch_bounds__(256)
__global__ void zgather(const int* __restrict__ offs5,
                        const unsigned long long* __restrict__ epack,
                        const float* __restrict__ Eprev,
                        float* __restrict__ Z, float* __restrict__ S)
{
    int wid = (blockIdx.x * 256 + threadIdx.x) >> 6;
    int lane = threadIdx.x & 63;
    if (wid >= NN) return;
    const int b = wid * RREL;

    // boundaries (shift-register, all static)
    int p    = offs5[b];
    int n1   = offs5[b + 1];
    int n2   = offs5[b + 2];
    int n3   = offs5[b + 3];
    int n4   = offs5[b + 4];
    int pend = offs5[b + 5];

    float* zr = Z + (size_t)wid * 320 + lane;
    const int INFP = 0x7fffffff;

    int r = 0;
    float zA = 0.f, zB = 0.f, zC = 0.f, zD = 0.f;
    float sA = 0.f, sB = 0.f, sC = 0.f, sD = 0.f;

#define WVAL(q) __uint_as_float((unsigned)((q) >> 32))
#define SRCI(q) ((unsigned)(q) & 0xFFFFFFFFu)

#define FLUSH_CHECK(pe)                                                     \
    while (r < 4 && (pe) == n1) {                                           \
        __builtin_nontemporal_store(zA + zB + zC + zD, &zr[(size_t)(r << 6)]); \
        if (lane == 0) __builtin_nontemporal_store(sA + sB + sC + sD, &S[b + r]); \
        zA = zB = zC = zD = 0.f; sA = sB = sC = sD = 0.f;                   \
        ++r; n1 = n2; n2 = n3; n3 = n4; n4 = INFP;                          \
    }

    for (; p + 8 <= pend; p += 8) {
        unsigned long long q0 = __builtin_nontemporal_load(&epack[p + 0]);
        unsigned long long q1 = __builtin_nontemporal_load(&epack[p + 1]);
        unsigned long long q2 = __builtin_nontemporal_load(&epack[p + 2]);
        unsigned long long q3 = __builtin_nontemporal_load(&epack[p + 3]);
        unsigned long long q4 = __builtin_nontemporal_load(&epack[p + 4]);
        unsigned long long q5 = __builtin_nontemporal_load(&epack[p + 5]);
        unsigned long long q6 = __builtin_nontemporal_load(&epack[p + 6]);
        unsigned long long q7 = __builtin_nontemporal_load(&epack[p + 7]);
        float v0 = Eprev[(size_t)SRCI(q0) * 64 + lane];
        float v1 = Eprev[(size_t)SRCI(q1) * 64 + lane];
        float v2 = Eprev[(size_t)SRCI(q2) * 64 + lane];
        float v3 = Eprev[(size_t)SRCI(q3) * 64 + lane];
        float v4 = Eprev[(size_t)SRCI(q4) * 64 + lane];
        float v5 = Eprev[(size_t)SRCI(q5) * 64 + lane];
        float v6 = Eprev[(size_t)SRCI(q6) * 64 + lane];
        float v7 = Eprev[(size_t)SRCI(q7) * 64 + lane];

        FLUSH_CHECK(p + 0);
        zA = fmaf(WVAL(q0), v0, zA); sA += WVAL(q0);
        FLUSH_CHECK(p + 1);
        zB = fmaf(WVAL(q1), v1, zB); sB += WVAL(q1);
        FLUSH_CHECK(p + 2);
        zC = fmaf(WVAL(q2), v2, zC); sC += WVAL(q2);
        FLUSH_CHECK(p + 3);
        zD = fmaf(WVAL(q3), v3, zD); sD += WVAL(q3);
        FLUSH_CHECK(p + 4);
        zA = fmaf(WVAL(q4), v4, zA); sA += WVAL(q4);
        FLUSH_CHECK(p + 5);
        zB = fmaf(WVAL(q5), v5, zB); sB += WVAL(q5);
        FLUSH_CHECK(p + 6);
        zC = fmaf(WVAL(q6), v6, zC); sC += WVAL(q6);
        FLUSH_CHECK(p + 7);
        zD = fmaf(WVAL(q7), v7, zD); sD += WVAL(q7);
    }
    for (; p < pend; ++p) {
        unsigned long long q = __builtin_nontemporal_load(&epack[p]);
        float v = Eprev[(size_t)SRCI(q) * 64 + lane];
        FLUSH_CHECK(p);
        zA = fmaf(WVAL(q), v, zA);
        sA += WVAL(q);
    }
    while (r < RREL) {
        __builtin_nontemporal_store(zA + zB + zC + zD, &zr[(size_t)(r << 6)]);
        if (lane == 0) __builtin_nontemporal_store(sA + sB + sC + sD, &S[b + r]);
        zA = zB = zC = zD = 0.f; sA = sB = sC = sD = 0.f;
        ++r;
    }
#undef FLUSH_CHECK
#undef WVAL
#undef SRCI
}

// ---------------------------------------------------------------------------
// prep_wfrag: relW [R][128][64] f32 -> split-bf16 MFMA fragments.
// ---------------------------------------------------------------------------
__launch_bounds__(256)
__global__ void prep_wfrag(const float* __restrict__ rel1_W, const float* __restrict__ rel2_W,
                           short8* __restrict__ wf1, short8* __restrict__ wf2)
{
    int bid = blockIdx.x;
    int layer = bid / 10, c = bid % 10;
    const float* relW = layer ? rel2_W : rel1_W;
    short8* wf = layer ? wf2 : wf1;
    int t = threadIdx.x;
    for (int sl = t; sl < 512; sl += 256) {
        int rid = sl >> 6, lane = sl & 63;
        int s = rid >> 2, nf = rid & 3;
        int g = lane >> 4, lc = lane & 15;
        int r = (c < 5) ? c : c - 5;
        const float* W = relW + (size_t)r * 8192 + ((c < 5) ? 0 : 4096);
        float v[8];
        #pragma unroll
        for (int j = 0; j < 8; ++j)
            v[j] = W[(size_t)(s * 32 + g * 8 + j) * 64 + nf * 16 + lc];
        float4 q0 = make_float4(v[0], v[1], v[2], v[3]);
        float4 q1 = make_float4(v[4], v[5], v[6], v[7]);
        short8 hi, lo;
        split8v(q0, q1, hi, lo);
        size_t slot = (size_t)c * 1024 + (size_t)((s * 4 + nf) * 64 + lane) * 2;
        wf[slot]     = hi;
        wf[slot + 1] = lo;
    }
}

// ---------------------------------------------------------------------------
// zgemm_mfma: 2-phase LDS pipeline (unchanged).
// ---------------------------------------------------------------------------
__launch_bounds__(512)
__global__ void zgemm_mfma(const float* __restrict__ Z,
                           const float* __restrict__ Eprev,
                           const short8* __restrict__ wf,
                           const float* __restrict__ relb,
                           const float* __restrict__ S,
                           float* __restrict__ Enext, int M)
{
    __shared__ short8 wlds[2][1024];   // 2 x 16 KB

    const int t = threadIdx.x;
    const int wid = t >> 6, lane = t & 63;
    const int lc = lane & 15, lg = lane >> 4;
    const int row0 = blockIdx.x * 128 + wid * 16;

    const int nA = row0 + lc;
    const bool okA = (nA < M);
    const int nodeA = okA ? nA : 0;

    const int sq = t >> 6, sl = t & 63;
    const int wrA = (sq * 2 + 0) * 64 + sl;
    const int wrB = (sq * 2 + 1) * 64 + sl;

    short8 eh[2], el[2];
    #pragma unroll
    for (int s = 0; s < 2; ++s) {
        const float* p = &Eprev[(size_t)nodeA * 64 + s * 32 + lg * 8];
        float4 q0 = okA ? *(const float4*)p       : make_float4(0,0,0,0);
        float4 q1 = okA ? *(const float4*)(p + 4) : make_float4(0,0,0,0);
        split8v(q0, q1, eh[s], el[s]);
    }

    float sD[4][RREL];
    #pragma unroll
    for (int i = 0; i < 4; ++i) {
        int nd = row0 + lg * 4 + i;
        int ns = (nd < M) ? nd : 0;
        #pragma unroll
        for (int r = 0; r < RREL; ++r)
            sD[i][r] = S[(size_t)ns * RREL + r];
    }

    {
        const short8* wp = wf + (size_t)t * 2;
        short8 sa = wp[0], sb = wp[1];
        wlds[0][wrA] = sa; wlds[0][wrB] = sb;
    }
    float4 az0[2], az1[2];
    {
        const float* p0 = &Z[(size_t)nodeA * 320 + 0 * 32 + lg * 8];
        const float* p1 = &Z[(size_t)nodeA * 320 + 1 * 32 + lg * 8];
        az0[0] = okA ? *(const float4*)p0       : make_float4(0,0,0,0);
        az0[1] = okA ? *(const float4*)(p0 + 4) : make_float4(0,0,0,0);
        az1[0] = okA ? *(const float4*)p1       : make_float4(0,0,0,0);
        az1[1] = okA ? *(const float4*)(p1 + 4) : make_float4(0,0,0,0);
    }
    __syncthreads();

    f32x4 acc[4];
    #pragma unroll
    for (int nf = 0; nf < 4; ++nf) acc[nf] = (f32x4){0.f, 0.f, 0.f, 0.f};

    short8 sreg_a, sreg_b;
    float4 pz0[2], pz1[2];

    #pragma unroll
    for (int c = 0; c < 10; ++c) {
        const int cb = c & 1;
        if (c < 9) {
            const short8* wp = wf + (size_t)(c + 1) * 1024 + (size_t)t * 2;
            sreg_a = wp[0]; sreg_b = wp[1];
        }
        if (c < 4) {
            const float* p0 = &Z[(size_t)nodeA * 320 + (c + 1) * 64 + 0 * 32 + lg * 8];
            const float* p1 = &Z[(size_t)nodeA * 320 + (c + 1) * 64 + 1 * 32 + lg * 8];
            pz0[0] = okA ? *(const float4*)p0       : make_float4(0,0,0,0);
            pz0[1] = okA ? *(const float4*)(p0 + 4) : make_float4(0,0,0,0);
            pz1[0] = okA ? *(const float4*)p1       : make_float4(0,0,0,0);
            pz1[1] = okA ? *(const float4*)(p1 + 4) : make_float4(0,0,0,0);
        }

        short8 Ah[2], Al[2];
        if (c < 5) {
            split8v(az0[0], az0[1], Ah[0], Al[0]);
            split8v(az1[0], az1[1], Ah[1], Al[1]);
        } else {
            Ah[0] = eh[0]; Al[0] = el[0];
            Ah[1] = eh[1]; Al[1] = el[1];
        }

        if (c < 5) {
            #pragma unroll
            for (int s = 0; s < 2; ++s)
                #pragma unroll
                for (int nf = 0; nf < 4; ++nf) {
                    short8 bh = wlds[cb][((s * 4 + nf) * 2 + 0) * 64 + lane];
                    short8 bl = wlds[cb][((s * 4 + nf) * 2 + 1) * 64 + lane];
                    acc[nf] = __builtin_amdgcn_mfma_f32_16x16x32_bf16(Ah[s], bh, acc[nf], 0, 0, 0);
                    acc[nf] = __builtin_amdgcn_mfma_f32_16x16x32_bf16(Al[s], bh, acc[nf], 0, 0, 0);
                    acc[nf] = __builtin_amdgcn_mfma_f32_16x16x32_bf16(Ah[s], bl, acc[nf], 0, 0, 0);
                }
        } else {
            f32x4 tmp[4];
            #pragma unroll
            for (int nf = 0; nf < 4; ++nf) tmp[nf] = (f32x4){0.f, 0.f, 0.f, 0.f};
            #pragma unroll
            for (int s = 0; s < 2; ++s)
                #pragma unroll
                for (int nf = 0; nf < 4; ++nf) {
                    short8 bh = wlds[cb][((s * 4 + nf) * 2 + 0) * 64 + lane];
                    short8 bl = wlds[cb][((s * 4 + nf) * 2 + 1) * 64 + lane];
                    tmp[nf] = __builtin_amdgcn_mfma_f32_16x16x32_bf16(Ah[s], bh, tmp[nf], 0, 0, 0);
                    tmp[nf] = __builtin_amdgcn_mfma_f32_16x16x32_bf16(Al[s], bh, tmp[nf], 0, 0, 0);
                    tmp[nf] = __builtin_amdgcn_mfma_f32_16x16x32_bf16(Ah[s], bl, tmp[nf], 0, 0, 0);
                }
            const int r = c - 5;
            #pragma unroll
            for (int nf = 0; nf < 4; ++nf)
                #pragma unroll
                for (int i = 0; i < 4; ++i)
                    acc[nf][i] += sD[i][r] * tmp[nf][i];
        }

        if (c < 4) {
            az0[0] = pz0[0]; az0[1] = pz0[1];
            az1[0] = pz1[0]; az1[1] = pz1[1];
        }

        if (c < 9) {
            __syncthreads();
            wlds[cb ^ 1][wrA] = sreg_a;
            wlds[cb ^ 1][wrB] = sreg_b;
            __syncthreads();
        }
    }

    float bbv[4][RREL];
    #pragma unroll
    for (int nf = 0; nf < 4; ++nf)
        #pragma unroll
        for (int r = 0; r < RREL; ++r)
            bbv[nf][r] = relb[r * 64 + nf * 16 + lc];

    #pragma unroll
    for (int i = 0; i < 4; ++i) {
        int nd = row0 + lg * 4 + i;
        if (nd >= M) continue;
        #pragma unroll
        for (int nf = 0; nf < 4; ++nf) {
            float v = acc[nf][i];
            #pragma unroll
            for (int r = 0; r < RREL; ++r)
                v += sD[i][r] * bbv[nf][r];
            Enext[(size_t)nd * 64 + nf * 16 + lc] = v;
        }
    }
}

// ---------------------------------------------------------------------------
// Fused output head: out = sum_s lrelu(Es @ Ws + bs)
// ---------------------------------------------------------------------------
__launch_bounds__(256)
__global__ void head_fused(const float* __restrict__ E0, const float* __restrict__ E1,
                           const float* __restrict__ E2,
                           const float* __restrict__ W0, const float* __restrict__ W1,
                           const float* __restrict__ W2,
                           const float* __restrict__ b0, const float* __restrict__ b1,
                           const float* __restrict__ b2,
                           float* __restrict__ out, int M)
{
    __shared__ float As[64][68];
    __shared__ float Bs[64][64];
    const int row0 = blockIdx.x * 64;
    const int t = threadIdx.x;
    const int tx = t & 15, ty = t >> 4;

    const float* Es[3] = {E0, E1, E2};
    const float* Ws[3] = {W0, W1, W2};
    const float* bs[3] = {b0, b1, b2};

    float acc[4][4] = {};

    #pragma unroll
    for (int s = 0; s < 3; ++s) {
        __syncthreads();
        {
            int arow = t >> 4, akk = (t & 15) << 2;
            #pragma unroll
            for (int rp = 0; rp < 64; rp += 16) {
                int r = rp + arow, gr = row0 + r;
                float4 v = make_float4(0.f, 0.f, 0.f, 0.f);
                if (gr < M) v = *(const float4*)&Es[s][(size_t)gr * 64 + akk];
                As[akk + 0][r] = v.x; As[akk + 1][r] = v.y;
                As[akk + 2][r] = v.z; As[akk + 3][r] = v.w;
            }
        }
        #pragma unroll
        for (int idx = t; idx < 1024; idx += 256) {
            int k = idx >> 4, c4 = (idx & 15) << 2;
            *(float4*)&Bs[k][c4] = *(const float4*)&Ws[s][(size_t)k * 64 + c4];
        }
        __syncthreads();

        float tmp[4][4] = {};
        #pragma unroll 8
        for (int k = 0; k < 64; ++k) {
            float4 av = *(const float4*)&As[k][ty * 4];
            float4 bv = *(const float4*)&Bs[k][tx * 4];
            float ar[4] = {av.x, av.y, av.z, av.w};
            float br[4] = {bv.x, bv.y, bv.z, bv.w};
            #pragma unroll
            for (int i = 0; i < 4; ++i)
                #pragma unroll
                for (int j = 0; j < 4; ++j)
                    tmp[i][j] = fmaf(ar[i], br[j], tmp[i][j]);
        }
        float bb[4];
        {
            const float* bp = bs[s] + tx * 4;
            bb[0] = bp[0]; bb[1] = bp[1]; bb[2] = bp[2]; bb[3] = bp[3];
        }
        #pragma unroll
        for (int i = 0; i < 4; ++i)
            #pragma unroll
            for (int j = 0; j < 4; ++j)
                acc[i][j] += lrelu(tmp[i][j] + bb[j]);
    }

    #pragma unroll
    for (int i = 0; i < 4; ++i) {
        int gr = row0 + ty * 4 + i;
        if (gr >= M) continue;
        *(float4*)&out[(size_t)gr * 64 + tx * 4] =
            make_float4(acc[i][0], acc[i][1], acc[i][2], acc[i][3]);
    }
}

// ---------------------------------------------------------------------------
// CSR build over (dst,type) keys
// ---------------------------------------------------------------------------
__launch_bounds__(256)
__global__ void deg5_hist(const int* __restrict__ dst, const int* __restrict__ etype,
                          int* __restrict__ deg5, int* __restrict__ slot5)
{
    int e = blockIdx.x * 256 + threadIdx.x;
    if (e < NE) slot5[e] = atomicAdd(&deg5[dst[e] * RREL + etype[e]], 1);
}

__launch_bounds__(256)
__global__ void b1_reduce(const int* __restrict__ deg5, int* __restrict__ b1)
{
    __shared__ int sh[256];
    int i = blockIdx.x * 256 + threadIdx.x;
    sh[threadIdx.x] = (i < NR) ? deg5[i] : 0;
    __syncthreads();
    for (int s = 128; s > 0; s >>= 1) {
        if (threadIdx.x < s) sh[threadIdx.x] += sh[threadIdx.x + s];
        __syncthreads();
    }
    if (threadIdx.x == 0) b1[blockIdx.x] = sh[0];
}

__launch_bounds__(256)
__global__ void scan_seq(int* __restrict__ b1, int n)
{
    __shared__ int sh[256];
    __shared__ int carry;
    if (threadIdx.x == 0) carry = 0;
    __syncthreads();
    for (int base = 0; base < n; base += 256) {
        int i = base + threadIdx.x;
        int v = (i < n) ? b1[i] : 0;
        sh[threadIdx.x] = v;
        __syncthreads();
        for (int off = 1; off < 256; off <<= 1) {
            int x = (threadIdx.x >= off) ? sh[threadIdx.x - off] : 0;
            __syncthreads();
            sh[threadIdx.x] += x;
            __syncthreads();
        }
        int excl = sh[threadIdx.x] - v + carry;
        if (i < n) b1[i] = excl;
        __syncthreads();
        if (threadIdx.x == 255) carry = excl + v;
        __syncthreads();
    }
}

__launch_bounds__(256)
__global__ void offs5_final(const int* __restrict__ deg5, const int* __restrict__ b1,
                            int* __restrict__ offs5)
{
    __shared__ int sh[256];
    int t = threadIdx.x;
    int i = blockIdx.x * 256 + t;
    int v = (i < NR) ? deg5[i] : 0;
    sh[t] = v;
    __syncthreads();
    for (int off = 1; off < 256; off <<= 1) {
        int x = (t >= off) ? sh[t - off] : 0;
        __syncthreads();
        sh[t] += x;
        __syncthreads();
    }
    int excl = sh[t] - v + b1[blockIdx.x];
    if (i <= NR) offs5[i] = excl;
}

// scatter: epack[offs5[dst*5+r] + slot5[e]] = {src, w}
__launch_bounds__(256)
__global__ void scatter_pass(const int* __restrict__ src, const int* __restrict__ dst,
                             const int* __restrict__ etype,
                             const float* __restrict__ etime,
                             const float* __restrict__ beta,
                             const float* __restrict__ lambda_p,
                             const int* __restrict__ slot5, const int* __restrict__ offs5,
                             unsigned long long* __restrict__ epack)
{
    int e = blockIdx.x * 256 + threadIdx.x;
    if (e >= NE) return;
    float b[12];
    #pragma unroll
    for (int j = 0; j < 12; ++j) b[j] = beta[j];
    const float* et = etime + (size_t)e * 12;
    float4 v0 = *(const float4*)(et);
    float4 v1 = *(const float4*)(et + 4);
    float4 v2 = *(const float4*)(et + 8);
    float logit = v0.x*b[0] + v0.y*b[1] + v0.z*b[2] + v0.w*b[3]
                + v1.x*b[4] + v1.y*b[5] + v1.z*b[6] + v1.w*b[7]
                + v2.x*b[8] + v2.y*b[9] + v2.z*b[10] + v2.w*b[11];
    float we = lambda_p[0] * expf(-logit);
    int p = offs5[dst[e] * RREL + etype[e]] + slot5[e];
    epack[p] = ((unsigned long long)__float_as_uint(we) << 32) | (unsigned)src[e];
}

// ---------------------------------------------------------------------------
extern "C" void kernel_launch(void* const* d_in, const int* in_sizes, int n_in,
                              void* d_out, int out_size, void* d_ws, size_t ws_size,
                              hipStream_t stream)
{
    const float* x        = (const float*)d_in[0];
    const int*   eidx     = (const int*)d_in[1];
    const int*   etype    = (const int*)d_in[2];
    const float* etime    = (const float*)d_in[3];
    const float* lambda_p = (const float*)d_in[4];
    const float* beta     = (const float*)d_in[5];
    const float* field_W  = (const float*)d_in[6];
    const float* field_b  = (const float*)d_in[7];
    const float* rel1_W   = (const float*)d_in[8];
    const float* rel1_b   = (const float*)d_in[9];
    const float* rel2_W   = (const float*)d_in[10];
    const float* rel2_b   = (const float*)d_in[11];
    const float* out0_W   = (const float*)d_in[12];
    const float* out0_b   = (const float*)d_in[13];
    const float* out1_W   = (const float*)d_in[14];
    const float* out1_b   = (const float*)d_in[15];
    const float* out2_W   = (const float*)d_in[16];
    const float* out2_b   = (const float*)d_in[17];
    const int* src = eidx;
    const int* dst = eidx + NE;
    float* out = (float*)d_out;

    char* wsb = (char*)d_ws;
    size_t off = 0;
    auto carve = [&](size_t bytes) -> void* {
        void* p = (void*)(wsb + off);
        off += (bytes + 255) & ~(size_t)255;
        return p;
    };
    int*   deg5   = (int*)carve((size_t)NR * 4);            // 1 MB
    int*   offs5  = (int*)carve((size_t)(NR + 1) * 4);      // 1 MB
    int*   b1     = (int*)carve((size_t)NB5 * 4);
    int*   slot5  = (int*)carve((size_t)NE * 4);            // 3.2 MB
    float* S      = (float*)carve((size_t)NR * 4);          // 1 MB
    unsigned long long* epack = (unsigned long long*)carve((size_t)NE * 8); // 6.4 MB
    float* e0     = (float*)carve((size_t)NN * 64 * 4);     // 12.8 MB
    float* e1     = (float*)carve((size_t)NN * 64 * 4);     // 12.8 MB
    float* e2     = (float*)carve((size_t)NN * 64 * 4);     // 12.8 MB
    float* Zb     = (float*)carve((size_t)NN * 320 * 4);    // 64 MB
    short8* wf1   = (short8*)carve((size_t)20 * 16384);     // 320 KB
    short8* wf2   = (short8*)carve((size_t)20 * 16384);     // 320 KB

    dim3 blk(256);
    const int NT64  = (NN + 63) / 64;       // 782
    const int NT128 = (NN + 127) / 128;     // 391
    const int EB = (NE + 255) / 256;
    const int GB = (NN * 64 + 255) / 256;   // one wave per node

    // ---- CSR build over (dst,type) + weight frag prep ----
    hipMemsetAsync(deg5, 0, (size_t)NR * 4, stream);
    deg5_hist<<<EB, blk, 0, stream>>>(dst, etype, deg5, slot5);
    prep_wfrag<<<20, blk, 0, stream>>>(rel1_W, rel2_W, wf1, wf2);
    b1_reduce<<<NB5, blk, 0, stream>>>(deg5, b1);
    scan_seq<<<1, blk, 0, stream>>>(b1, NB5);
    offs5_final<<<NB5, blk, 0, stream>>>(deg5, b1, offs5);
    scatter_pass<<<EB, blk, 0, stream>>>(src, dst, etype, etime, beta, lambda_p,
                                         slot5, offs5, epack);

    // ---- e0 = x @ field_W + field_b ----
    gemm_tile<128><<<dim3(NT64), blk, 0, stream>>>(x, 128, field_W, field_b, e0, NN);

    // ---- layer 1 ----
    zgather<<<GB, blk, 0, stream>>>(offs5, epack, e0, Zb, S);
    zgemm_mfma<<<dim3(NT128), dim3(512), 0, stream>>>(Zb, e0, wf1, rel1_b, S, e1, NN);

    // ---- layer 2 ----
    zgather<<<GB, blk, 0, stream>>>(offs5, epack, e1, Zb, S);
    zgemm_mfma<<<dim3(NT128), dim3(512), 0, stream>>>(Zb, e1, wf2, rel2_b, S, e2, NN);

    // ---- output head (single pass) ----
    head_fused<<<dim3(NT64), blk, 0, stream>>>(e0, e1, e2, out0_W, out1_W, out2_W,
                                               out0_b, out1_b, out2_b, out, NN);
}

// Round 13
// 273.120 us; speedup vs baseline: 1.1531x; 1.1531x over previous
//
#include <hip/hip_runtime.h>
#include <cstdint>
#include <cstddef>

#define NN 50000
#define NE 800000
#define RREL 5
#define NR (NN * RREL)                 // 250000 (dst,type) keys
#define NB5 ((NR + 255) / 256)         // 977

typedef __attribute__((ext_vector_type(8))) short short8;   // 8 bf16 (4 VGPRs)
typedef __attribute__((ext_vector_type(4))) float f32x4;
typedef unsigned short ushort_t;

static __device__ __forceinline__ float lrelu(float v) { return v > 0.f ? v : 0.01f * v; }

static __device__ __forceinline__ unsigned short f32_bf16_rn(float x) {
    unsigned u = __float_as_uint(x);
    return (unsigned short)((u + 0x7FFFu + ((u >> 16) & 1u)) >> 16);
}
static __device__ __forceinline__ float bf16_f32(unsigned short h) {
    return __uint_as_float(((unsigned)h) << 16);
}

// split 8 f32 (two float4) into bf16 hi + lo (x ~= hi + lo)
static __device__ __forceinline__ void split8v(float4 q0, float4 q1, short8& hi, short8& lo) {
    float v[8] = {q0.x, q0.y, q0.z, q0.w, q1.x, q1.y, q1.z, q1.w};
    #pragma unroll
    for (int j = 0; j < 8; ++j) {
        unsigned short h = f32_bf16_rn(v[j]);
        float hf = __uint_as_float(((unsigned)h) << 16);
        unsigned short l = f32_bf16_rn(v[j] - hf);
        hi[j] = (short)h; lo[j] = (short)l;
    }
}

// ---------------------------------------------------------------------------
// 64x64-tile f32 GEMM (e0 = x @ field_W + field_b, K=128) + bf16 shadow out
// ---------------------------------------------------------------------------
template<int K>
__launch_bounds__(256)
__global__ void gemm_tile(const float* __restrict__ A, int lda,
                          const float* __restrict__ B0,
                          const float* __restrict__ bias,
                          float* __restrict__ C, ushort_t* __restrict__ Cb, int M)
{
    __shared__ float As[64][68];
    __shared__ float Bs[64][64];
    const int row0 = blockIdx.x * 64;
    const int t = threadIdx.x;
    const int tx = t & 15, ty = t >> 4;

    float acc[4][4] = {};

    for (int kc = 0; kc < K; kc += 64) {
        {
            int arow = t >> 4, akk = (t & 15) << 2;
            #pragma unroll
            for (int rp = 0; rp < 64; rp += 16) {
                int r = rp + arow, gr = row0 + r;
                float4 v = make_float4(0.f, 0.f, 0.f, 0.f);
                if (gr < M) v = *(const float4*)&A[(size_t)gr * lda + kc + akk];
                As[akk + 0][r] = v.x; As[akk + 1][r] = v.y;
                As[akk + 2][r] = v.z; As[akk + 3][r] = v.w;
            }
        }
        #pragma unroll
        for (int idx = t; idx < 1024; idx += 256) {
            int k = idx >> 4, c4 = (idx & 15) << 2;
            *(float4*)&Bs[k][c4] = *(const float4*)&B0[(size_t)(kc + k) * 64 + c4];
        }
        __syncthreads();

        #pragma unroll 8
        for (int k = 0; k < 64; ++k) {
            float4 av = *(const float4*)&As[k][ty * 4];
            float4 bv = *(const float4*)&Bs[k][tx * 4];
            float ar[4] = {av.x, av.y, av.z, av.w};
            float br[4] = {bv.x, bv.y, bv.z, bv.w};
            #pragma unroll
            for (int i = 0; i < 4; ++i)
                #pragma unroll
                for (int j = 0; j < 4; ++j)
                    acc[i][j] = fmaf(ar[i], br[j], acc[i][j]);
        }
        __syncthreads();
    }

    float bb[4];
    {
        const float* bp = bias + tx * 4;
        bb[0] = bp[0]; bb[1] = bp[1]; bb[2] = bp[2]; bb[3] = bp[3];
    }
    #pragma unroll
    for (int i = 0; i < 4; ++i) {
        int gr = row0 + ty * 4 + i;
        if (gr >= M) continue;
        float v0 = acc[i][0] + bb[0], v1 = acc[i][1] + bb[1];
        float v2 = acc[i][2] + bb[2], v3 = acc[i][3] + bb[3];
        *(float4*)&C[(size_t)gr * 64 + tx * 4] = make_float4(v0, v1, v2, v3);
        ushort4 h;
        h.x = f32_bf16_rn(v0); h.y = f32_bf16_rn(v1);
        h.z = f32_bf16_rn(v2); h.w = f32_bf16_rn(v3);
        *(ushort4*)&Cb[(size_t)gr * 64 + tx * 4] = h;
    }
}

// ---------------------------------------------------------------------------
// zgather v5: R10 structure (4-deep pipelined full-range walk, wave-uniform
// flush), but features read from the bf16 shadow table (half traffic,
// half L2 working set).
// ---------------------------------------------------------------------------
__launch_bounds__(256)
__global__ void zgather(const int* __restrict__ offs5,
                        const unsigned long long* __restrict__ epack,
                        const ushort_t* __restrict__ Eb,
                        float* __restrict__ Z, float* __restrict__ S)
{
    int wid = (blockIdx.x * 256 + threadIdx.x) >> 6;
    int lane = threadIdx.x & 63;
    if (wid >= NN) return;
    const int b = wid * RREL;

    int p    = offs5[b];
    int n1   = offs5[b + 1];
    int n2   = offs5[b + 2];
    int n3   = offs5[b + 3];
    int n4   = offs5[b + 4];
    int pend = offs5[b + 5];

    float* zr = Z + (size_t)wid * 320 + lane;
    const int INFP = 0x7fffffff;

    int r = 0;
    float zA = 0.f, zB = 0.f, sA = 0.f, sB = 0.f;

#define WVAL(q) __uint_as_float((unsigned)((q) >> 32))
#define SRCI(q) ((unsigned)(q) & 0xFFFFFFFFu)

#define FLUSH_CHECK(pe)                                                     \
    while (r < 4 && (pe) == n1) {                                           \
        zr[(size_t)(r << 6)] = zA + zB;                                     \
        if (lane == 0) S[b + r] = sA + sB;                                  \
        zA = zB = 0.f; sA = sB = 0.f;                                       \
        ++r; n1 = n2; n2 = n3; n3 = n4; n4 = INFP;                          \
    }

    for (; p + 4 <= pend; p += 4) {
        unsigned long long q0 = epack[p + 0];
        unsigned long long q1 = epack[p + 1];
        unsigned long long q2 = epack[p + 2];
        unsigned long long q3 = epack[p + 3];
        float v0 = bf16_f32(Eb[(size_t)SRCI(q0) * 64 + lane]);
        float v1 = bf16_f32(Eb[(size_t)SRCI(q1) * 64 + lane]);
        float v2 = bf16_f32(Eb[(size_t)SRCI(q2) * 64 + lane]);
        float v3 = bf16_f32(Eb[(size_t)SRCI(q3) * 64 + lane]);

        FLUSH_CHECK(p + 0);
        zA = fmaf(WVAL(q0), v0, zA); sA += WVAL(q0);
        FLUSH_CHECK(p + 1);
        zB = fmaf(WVAL(q1), v1, zB); sB += WVAL(q1);
        FLUSH_CHECK(p + 2);
        zA = fmaf(WVAL(q2), v2, zA); sA += WVAL(q2);
        FLUSH_CHECK(p + 3);
        zB = fmaf(WVAL(q3), v3, zB); sB += WVAL(q3);
    }
    for (; p < pend; ++p) {
        unsigned long long q = epack[p];
        float v = bf16_f32(Eb[(size_t)SRCI(q) * 64 + lane]);
        FLUSH_CHECK(p);
        zA = fmaf(WVAL(q), v, zA);
        sA += WVAL(q);
    }
    while (r < RREL) {
        zr[(size_t)(r << 6)] = zA + zB;
        if (lane == 0) S[b + r] = sA + sB;
        zA = zB = 0.f; sA = sB = 0.f;
        ++r;
    }
#undef FLUSH_CHECK
#undef WVAL
#undef SRCI
}

// ---------------------------------------------------------------------------
// prep_wfrag: relW [R][128][64] f32 -> split-bf16 MFMA fragments.
// ---------------------------------------------------------------------------
__launch_bounds__(256)
__global__ void prep_wfrag(const float* __restrict__ rel1_W, const float* __restrict__ rel2_W,
                           short8* __restrict__ wf1, short8* __restrict__ wf2)
{
    int bid = blockIdx.x;
    int layer = bid / 10, c = bid % 10;
    const float* relW = layer ? rel2_W : rel1_W;
    short8* wf = layer ? wf2 : wf1;
    int t = threadIdx.x;
    for (int sl = t; sl < 512; sl += 256) {
        int rid = sl >> 6, lane = sl & 63;
        int s = rid >> 2, nf = rid & 3;
        int g = lane >> 4, lc = lane & 15;
        int r = (c < 5) ? c : c - 5;
        const float* W = relW + (size_t)r * 8192 + ((c < 5) ? 0 : 4096);
        float v[8];
        #pragma unroll
        for (int j = 0; j < 8; ++j)
            v[j] = W[(size_t)(s * 32 + g * 8 + j) * 64 + nf * 16 + lc];
        float4 q0 = make_float4(v[0], v[1], v[2], v[3]);
        float4 q1 = make_float4(v[4], v[5], v[6], v[7]);
        short8 hi, lo;
        split8v(q0, q1, hi, lo);
        size_t slot = (size_t)c * 1024 + (size_t)((s * 4 + nf) * 64 + lane) * 2;
        wf[slot]     = hi;
        wf[slot + 1] = lo;
    }
}

// ---------------------------------------------------------------------------
// zgemm_mfma: 2-phase LDS pipeline; epilogue optionally emits bf16 shadow.
// ---------------------------------------------------------------------------
__launch_bounds__(512)
__global__ void zgemm_mfma(const float* __restrict__ Z,
                           const float* __restrict__ Eprev,
                           const short8* __restrict__ wf,
                           const float* __restrict__ relb,
                           const float* __restrict__ S,
                           float* __restrict__ Enext, ushort_t* __restrict__ Enb, int M)
{
    __shared__ short8 wlds[2][1024];   // 2 x 16 KB

    const int t = threadIdx.x;
    const int wid = t >> 6, lane = t & 63;
    const int lc = lane & 15, lg = lane >> 4;
    const int row0 = blockIdx.x * 128 + wid * 16;

    const int nA = row0 + lc;
    const bool okA = (nA < M);
    const int nodeA = okA ? nA : 0;

    const int sq = t >> 6, sl = t & 63;
    const int wrA = (sq * 2 + 0) * 64 + sl;
    const int wrB = (sq * 2 + 1) * 64 + sl;

    short8 eh[2], el[2];
    #pragma unroll
    for (int s = 0; s < 2; ++s) {
        const float* p = &Eprev[(size_t)nodeA * 64 + s * 32 + lg * 8];
        float4 q0 = okA ? *(const float4*)p       : make_float4(0,0,0,0);
        float4 q1 = okA ? *(const float4*)(p + 4) : make_float4(0,0,0,0);
        split8v(q0, q1, eh[s], el[s]);
    }

    float sD[4][RREL];
    #pragma unroll
    for (int i = 0; i < 4; ++i) {
        int nd = row0 + lg * 4 + i;
        int ns = (nd < M) ? nd : 0;
        #pragma unroll
        for (int r = 0; r < RREL; ++r)
            sD[i][r] = S[(size_t)ns * RREL + r];
    }

    {
        const short8* wp = wf + (size_t)t * 2;
        short8 sa = wp[0], sb = wp[1];
        wlds[0][wrA] = sa; wlds[0][wrB] = sb;
    }
    float4 az0[2], az1[2];
    {
        const float* p0 = &Z[(size_t)nodeA * 320 + 0 * 32 + lg * 8];
        const float* p1 = &Z[(size_t)nodeA * 320 + 1 * 32 + lg * 8];
        az0[0] = okA ? *(const float4*)p0       : make_float4(0,0,0,0);
        az0[1] = okA ? *(const float4*)(p0 + 4) : make_float4(0,0,0,0);
        az1[0] = okA ? *(const float4*)p1       : make_float4(0,0,0,0);
        az1[1] = okA ? *(const float4*)(p1 + 4) : make_float4(0,0,0,0);
    }
    __syncthreads();

    f32x4 acc[4];
    #pragma unroll
    for (int nf = 0; nf < 4; ++nf) acc[nf] = (f32x4){0.f, 0.f, 0.f, 0.f};

    short8 sreg_a, sreg_b;
    float4 pz0[2], pz1[2];

    #pragma unroll
    for (int c = 0; c < 10; ++c) {
        const int cb = c & 1;
        if (c < 9) {
            const short8* wp = wf + (size_t)(c + 1) * 1024 + (size_t)t * 2;
            sreg_a = wp[0]; sreg_b = wp[1];
        }
        if (c < 4) {
            const float* p0 = &Z[(size_t)nodeA * 320 + (c + 1) * 64 + 0 * 32 + lg * 8];
            const float* p1 = &Z[(size_t)nodeA * 320 + (c + 1) * 64 + 1 * 32 + lg * 8];
            pz0[0] = okA ? *(const float4*)p0       : make_float4(0,0,0,0);
            pz0[1] = okA ? *(const float4*)(p0 + 4) : make_float4(0,0,0,0);
            pz1[0] = okA ? *(const float4*)p1       : make_float4(0,0,0,0);
            pz1[1] = okA ? *(const float4*)(p1 + 4) : make_float4(0,0,0,0);
        }

        short8 Ah[2], Al[2];
        if (c < 5) {
            split8v(az0[0], az0[1], Ah[0], Al[0]);
            split8v(az1[0], az1[1], Ah[1], Al[1]);
        } else {
            Ah[0] = eh[0]; Al[0] = el[0];
            Ah[1] = eh[1]; Al[1] = el[1];
        }

        if (c < 5) {
            #pragma unroll
            for (int s = 0; s < 2; ++s)
                #pragma unroll
                for (int nf = 0; nf < 4; ++nf) {
                    short8 bh = wlds[cb][((s * 4 + nf) * 2 + 0) * 64 + lane];
                    short8 bl = wlds[cb][((s * 4 + nf) * 2 + 1) * 64 + lane];
                    acc[nf] = __builtin_amdgcn_mfma_f32_16x16x32_bf16(Ah[s], bh, acc[nf], 0, 0, 0);
                    acc[nf] = __builtin_amdgcn_mfma_f32_16x16x32_bf16(Al[s], bh, acc[nf], 0, 0, 0);
                    acc[nf] = __builtin_amdgcn_mfma_f32_16x16x32_bf16(Ah[s], bl, acc[nf], 0, 0, 0);
                }
        } else {
            f32x4 tmp[4];
            #pragma unroll
            for (int nf = 0; nf < 4; ++nf) tmp[nf] = (f32x4){0.f, 0.f, 0.f, 0.f};
            #pragma unroll
            for (int s = 0; s < 2; ++s)
                #pragma unroll
                for (int nf = 0; nf < 4; ++nf) {
                    short8 bh = wlds[cb][((s * 4 + nf) * 2 + 0) * 64 + lane];
                    short8 bl = wlds[cb][((s * 4 + nf) * 2 + 1) * 64 + lane];
                    tmp[nf] = __builtin_amdgcn_mfma_f32_16x16x32_bf16(Ah[s], bh, tmp[nf], 0, 0, 0);
                    tmp[nf] = __builtin_amdgcn_mfma_f32_16x16x32_bf16(Al[s], bh, tmp[nf], 0, 0, 0);
                    tmp[nf] = __builtin_amdgcn_mfma_f32_16x16x32_bf16(Ah[s], bl, tmp[nf], 0, 0, 0);
                }
            const int r = c - 5;
            #pragma unroll
            for (int nf = 0; nf < 4; ++nf)
                #pragma unroll
                for (int i = 0; i < 4; ++i)
                    acc[nf][i] += sD[i][r] * tmp[nf][i];
        }

        if (c < 4) {
            az0[0] = pz0[0]; az0[1] = pz0[1];
            az1[0] = pz1[0]; az1[1] = pz1[1];
        }

        if (c < 9) {
            __syncthreads();
            wlds[cb ^ 1][wrA] = sreg_a;
            wlds[cb ^ 1][wrB] = sreg_b;
            __syncthreads();
        }
    }

    float bbv[4][RREL];
    #pragma unroll
    for (int nf = 0; nf < 4; ++nf)
        #pragma unroll
        for (int r = 0; r < RREL; ++r)
            bbv[nf][r] = relb[r * 64 + nf * 16 + lc];

    #pragma unroll
    for (int i = 0; i < 4; ++i) {
        int nd = row0 + lg * 4 + i;
        if (nd >= M) continue;
        #pragma unroll
        for (int nf = 0; nf < 4; ++nf) {
            float v = acc[nf][i];
            #pragma unroll
            for (int r = 0; r < RREL; ++r)
                v += sD[i][r] * bbv[nf][r];
            Enext[(size_t)nd * 64 + nf * 16 + lc] = v;
            if (Enb) Enb[(size_t)nd * 64 + nf * 16 + lc] = f32_bf16_rn(v);
        }
    }
}

// ---------------------------------------------------------------------------
// Fused output head: out = sum_s lrelu(Es @ Ws + bs)
// ---------------------------------------------------------------------------
__launch_bounds__(256)
__global__ void head_fused(const float* __restrict__ E0, const float* __restrict__ E1,
                           const float* __restrict__ E2,
                           const float* __restrict__ W0, const float* __restrict__ W1,
                           const float* __restrict__ W2,
                           const float* __restrict__ b0, const float* __restrict__ b1,
                           const float* __restrict__ b2,
                           float* __restrict__ out, int M)
{
    __shared__ float As[64][68];
    __shared__ float Bs[64][64];
    const int row0 = blockIdx.x * 64;
    const int t = threadIdx.x;
    const int tx = t & 15, ty = t >> 4;

    const float* Es[3] = {E0, E1, E2};
    const float* Ws[3] = {W0, W1, W2};
    const float* bs[3] = {b0, b1, b2};

    float acc[4][4] = {};

    #pragma unroll
    for (int s = 0; s < 3; ++s) {
        __syncthreads();
        {
            int arow = t >> 4, akk = (t & 15) << 2;
            #pragma unroll
            for (int rp = 0; rp < 64; rp += 16) {
                int r = rp + arow, gr = row0 + r;
                float4 v = make_float4(0.f, 0.f, 0.f, 0.f);
                if (gr < M) v = *(const float4*)&Es[s][(size_t)gr * 64 + akk];
                As[akk + 0][r] = v.x; As[akk + 1][r] = v.y;
                As[akk + 2][r] = v.z; As[akk + 3][r] = v.w;
            }
        }
        #pragma unroll
        for (int idx = t; idx < 1024; idx += 256) {
            int k = idx >> 4, c4 = (idx & 15) << 2;
            *(float4*)&Bs[k][c4] = *(const float4*)&Ws[s][(size_t)k * 64 + c4];
        }
        __syncthreads();

        float tmp[4][4] = {};
        #pragma unroll 8
        for (int k = 0; k < 64; ++k) {
            float4 av = *(const float4*)&As[k][ty * 4];
            float4 bv = *(const float4*)&Bs[k][tx * 4];
            float ar[4] = {av.x, av.y, av.z, av.w};
            float br[4] = {bv.x, bv.y, bv.z, bv.w};
            #pragma unroll
            for (int i = 0; i < 4; ++i)
                #pragma unroll
                for (int j = 0; j < 4; ++j)
                    tmp[i][j] = fmaf(ar[i], br[j], tmp[i][j]);
        }
        float bb[4];
        {
            const float* bp = bs[s] + tx * 4;
            bb[0] = bp[0]; bb[1] = bp[1]; bb[2] = bp[2]; bb[3] = bp[3];
        }
        #pragma unroll
        for (int i = 0; i < 4; ++i)
            #pragma unroll
            for (int j = 0; j < 4; ++j)
                acc[i][j] += lrelu(tmp[i][j] + bb[j]);
    }

    #pragma unroll
    for (int i = 0; i < 4; ++i) {
        int gr = row0 + ty * 4 + i;
        if (gr >= M) continue;
        *(float4*)&out[(size_t)gr * 64 + tx * 4] =
            make_float4(acc[i][0], acc[i][1], acc[i][2], acc[i][3]);
    }
}

// ---------------------------------------------------------------------------
// CSR build over (dst,type) keys
// ---------------------------------------------------------------------------
__launch_bounds__(256)
__global__ void deg5_hist(const int* __restrict__ dst, const int* __restrict__ etype,
                          int* __restrict__ deg5, int* __restrict__ slot5)
{
    int e = blockIdx.x * 256 + threadIdx.x;
    if (e < NE) slot5[e] = atomicAdd(&deg5[dst[e] * RREL + etype[e]], 1);
}

__launch_bounds__(256)
__global__ void b1_reduce(const int* __restrict__ deg5, int* __restrict__ b1)
{
    __shared__ int sh[256];
    int i = blockIdx.x * 256 + threadIdx.x;
    sh[threadIdx.x] = (i < NR) ? deg5[i] : 0;
    __syncthreads();
    for (int s = 128; s > 0; s >>= 1) {
        if (threadIdx.x < s) sh[threadIdx.x] += sh[threadIdx.x + s];
        __syncthreads();
    }
    if (threadIdx.x == 0) b1[blockIdx.x] = sh[0];
}

__launch_bounds__(256)
__global__ void scan_seq(int* __restrict__ b1, int n)
{
    __shared__ int sh[256];
    __shared__ int carry;
    if (threadIdx.x == 0) carry = 0;
    __syncthreads();
    for (int base = 0; base < n; base += 256) {
        int i = base + threadIdx.x;
        int v = (i < n) ? b1[i] : 0;
        sh[threadIdx.x] = v;
        __syncthreads();
        for (int off = 1; off < 256; off <<= 1) {
            int x = (threadIdx.x >= off) ? sh[threadIdx.x - off] : 0;
            __syncthreads();
            sh[threadIdx.x] += x;
            __syncthreads();
        }
        int excl = sh[threadIdx.x] - v + carry;
        if (i < n) b1[i] = excl;
        __syncthreads();
        if (threadIdx.x == 255) carry = excl + v;
        __syncthreads();
    }
}

__launch_bounds__(256)
__global__ void offs5_final(const int* __restrict__ deg5, const int* __restrict__ b1,
                            int* __restrict__ offs5)
{
    __shared__ int sh[256];
    int t = threadIdx.x;
    int i = blockIdx.x * 256 + t;
    int v = (i < NR) ? deg5[i] : 0;
    sh[t] = v;
    __syncthreads();
    for (int off = 1; off < 256; off <<= 1) {
        int x = (t >= off) ? sh[t - off] : 0;
        __syncthreads();
        sh[t] += x;
        __syncthreads();
    }
    int excl = sh[t] - v + b1[blockIdx.x];
    if (i <= NR) offs5[i] = excl;
}

// scatter: epack[offs5[dst*5+r] + slot5[e]] = {w, src} packed u64
__launch_bounds__(256)
__global__ void scatter_pass(const int* __restrict__ src, const int* __restrict__ dst,
                             const int* __restrict__ etype,
                             const float* __restrict__ etime,
                             const float* __restrict__ beta,
                             const float* __restrict__ lambda_p,
                             const int* __restrict__ slot5, const int* __restrict__ offs5,
                             unsigned long long* __restrict__ epack)
{
    int e = blockIdx.x * 256 + threadIdx.x;
    if (e >= NE) return;
    float b[12];
    #pragma unroll
    for (int j = 0; j < 12; ++j) b[j] = beta[j];
    const float* et = etime + (size_t)e * 12;
    float4 v0 = *(const float4*)(et);
    float4 v1 = *(const float4*)(et + 4);
    float4 v2 = *(const float4*)(et + 8);
    float logit = v0.x*b[0] + v0.y*b[1] + v0.z*b[2] + v0.w*b[3]
                + v1.x*b[4] + v1.y*b[5] + v1.z*b[6] + v1.w*b[7]
                + v2.x*b[8] + v2.y*b[9] + v2.z*b[10] + v2.w*b[11];
    float we = lambda_p[0] * expf(-logit);
    int p = offs5[dst[e] * RREL + etype[e]] + slot5[e];
    epack[p] = ((unsigned long long)__float_as_uint(we) << 32) | (unsigned)src[e];
}

// ---------------------------------------------------------------------------
extern "C" void kernel_launch(void* const* d_in, const int* in_sizes, int n_in,
                              void* d_out, int out_size, void* d_ws, size_t ws_size,
                              hipStream_t stream)
{
    const float* x        = (const float*)d_in[0];
    const int*   eidx     = (const int*)d_in[1];
    const int*   etype    = (const int*)d_in[2];
    const float* etime    = (const float*)d_in[3];
    const float* lambda_p = (const float*)d_in[4];
    const float* beta     = (const float*)d_in[5];
    const float* field_W  = (const float*)d_in[6];
    const float* field_b  = (const float*)d_in[7];
    const float* rel1_W   = (const float*)d_in[8];
    const float* rel1_b   = (const float*)d_in[9];
    const float* rel2_W   = (const float*)d_in[10];
    const float* rel2_b   = (const float*)d_in[11];
    const float* out0_W   = (const float*)d_in[12];
    const float* out0_b   = (const float*)d_in[13];
    const float* out1_W   = (const float*)d_in[14];
    const float* out1_b   = (const float*)d_in[15];
    const float* out2_W   = (const float*)d_in[16];
    const float* out2_b   = (const float*)d_in[17];
    const int* src = eidx;
    const int* dst = eidx + NE;
    float* out = (float*)d_out;

    char* wsb = (char*)d_ws;
    size_t off = 0;
    auto carve = [&](size_t bytes) -> void* {
        void* p = (void*)(wsb + off);
        off += (bytes + 255) & ~(size_t)255;
        return p;
    };
    int*   deg5   = (int*)carve((size_t)NR * 4);            // 1 MB
    int*   offs5  = (int*)carve((size_t)(NR + 1) * 4);      // 1 MB
    int*   b1     = (int*)carve((size_t)NB5 * 4);
    int*   slot5  = (int*)carve((size_t)NE * 4);            // 3.2 MB
    float* S      = (float*)carve((size_t)NR * 4);          // 1 MB
    unsigned long long* epack = (unsigned long long*)carve((size_t)NE * 8); // 6.4 MB
    float* e0     = (float*)carve((size_t)NN * 64 * 4);     // 12.8 MB
    float* e1     = (float*)carve((size_t)NN * 64 * 4);     // 12.8 MB
    float* e2     = (float*)carve((size_t)NN * 64 * 4);     // 12.8 MB
    ushort_t* e0b = (ushort_t*)carve((size_t)NN * 64 * 2);  // 6.4 MB bf16 shadow
    ushort_t* e1b = (ushort_t*)carve((size_t)NN * 64 * 2);  // 6.4 MB bf16 shadow
    float* Zb     = (float*)carve((size_t)NN * 320 * 4);    // 64 MB
    short8* wf1   = (short8*)carve((size_t)20 * 16384);     // 320 KB
    short8* wf2   = (short8*)carve((size_t)20 * 16384);     // 320 KB

    dim3 blk(256);
    const int NT64  = (NN + 63) / 64;       // 782
    const int NT128 = (NN + 127) / 128;     // 391
    const int EB = (NE + 255) / 256;
    const int GB = (NN * 64 + 255) / 256;   // one wave per node

    // ---- CSR build over (dst,type) + weight frag prep ----
    hipMemsetAsync(deg5, 0, (size_t)NR * 4, stream);
    deg5_hist<<<EB, blk, 0, stream>>>(dst, etype, deg5, slot5);
    prep_wfrag<<<20, blk, 0, stream>>>(rel1_W, rel2_W, wf1, wf2);
    b1_reduce<<<NB5, blk, 0, stream>>>(deg5, b1);
    scan_seq<<<1, blk, 0, stream>>>(b1, NB5);
    offs5_final<<<NB5, blk, 0, stream>>>(deg5, b1, offs5);
    scatter_pass<<<EB, blk, 0, stream>>>(src, dst, etype, etime, beta, lambda_p,
                                         slot5, offs5, epack);

    // ---- e0 = x @ field_W + field_b (+ bf16 shadow) ----
    gemm_tile<128><<<dim3(NT64), blk, 0, stream>>>(x, 128, field_W, field_b, e0, e0b, NN);

    // ---- layer 1 ----
    zgather<<<GB, blk, 0, stream>>>(offs5, epack, e0b, Zb, S);
    zgemm_mfma<<<dim3(NT128), dim3(512), 0, stream>>>(Zb, e0, wf1, rel1_b, S, e1, e1b, NN);

    // ---- layer 2 ----
    zgather<<<GB, blk, 0, stream>>>(offs5, epack, e1b, Zb, S);
    zgemm_mfma<<<dim3(NT128), dim3(512), 0, stream>>>(Zb, e1, wf2, rel2_b, S, e2, nullptr, NN);

    // ---- output head (single pass) ----
    head_fused<<<dim3(NT64), blk, 0, stream>>>(e0, e1, e2, out0_W, out1_W, out2_W,
                                               out0_b, out1_b, out2_b, out, NN);
}

// Round 14
// 258.085 us; speedup vs baseline: 1.2203x; 1.0583x over previous
//
#include <hip/hip_runtime.h>
#include <cstdint>
#include <cstddef>

#define NN 50000
#define NE 800000
#define RREL 5
#define NR (NN * RREL)                 // 250000 (dst,type) keys
#define NB5 ((NR + 255) / 256)         // 977

typedef __attribute__((ext_vector_type(8))) short short8;   // 8 bf16 (4 VGPRs)
typedef __attribute__((ext_vector_type(4))) float f32x4;
typedef unsigned short ushort_t;

static __device__ __forceinline__ float lrelu(float v) { return v > 0.f ? v : 0.01f * v; }

static __device__ __forceinline__ unsigned short f32_bf16_rn(float x) {
    unsigned u = __float_as_uint(x);
    return (unsigned short)((u + 0x7FFFu + ((u >> 16) & 1u)) >> 16);
}
static __device__ __forceinline__ float bf16_f32(unsigned short h) {
    return __uint_as_float(((unsigned)h) << 16);
}

// split 8 f32 (two float4) into bf16 hi + lo (x ~= hi + lo)
static __device__ __forceinline__ void split8v(float4 q0, float4 q1, short8& hi, short8& lo) {
    float v[8] = {q0.x, q0.y, q0.z, q0.w, q1.x, q1.y, q1.z, q1.w};
    #pragma unroll
    for (int j = 0; j < 8; ++j) {
        unsigned short h = f32_bf16_rn(v[j]);
        float hf = __uint_as_float(((unsigned)h) << 16);
        unsigned short l = f32_bf16_rn(v[j] - hf);
        hi[j] = (short)h; lo[j] = (short)l;
    }
}

static __device__ __forceinline__ short8 zero8() {
    short8 z = {0, 0, 0, 0, 0, 0, 0, 0};
    return z;
}

// ---------------------------------------------------------------------------
// 64x64-tile f32 GEMM (e0 = x @ field_W + field_b, K=128) + bf16 shadow out
// ---------------------------------------------------------------------------
template<int K>
__launch_bounds__(256)
__global__ void gemm_tile(const float* __restrict__ A, int lda,
                          const float* __restrict__ B0,
                          const float* __restrict__ bias,
                          float* __restrict__ C, ushort_t* __restrict__ Cb, int M)
{
    __shared__ float As[64][68];
    __shared__ float Bs[64][64];
    const int row0 = blockIdx.x * 64;
    const int t = threadIdx.x;
    const int tx = t & 15, ty = t >> 4;

    float acc[4][4] = {};

    for (int kc = 0; kc < K; kc += 64) {
        {
            int arow = t >> 4, akk = (t & 15) << 2;
            #pragma unroll
            for (int rp = 0; rp < 64; rp += 16) {
                int r = rp + arow, gr = row0 + r;
                float4 v = make_float4(0.f, 0.f, 0.f, 0.f);
                if (gr < M) v = *(const float4*)&A[(size_t)gr * lda + kc + akk];
                As[akk + 0][r] = v.x; As[akk + 1][r] = v.y;
                As[akk + 2][r] = v.z; As[akk + 3][r] = v.w;
            }
        }
        #pragma unroll
        for (int idx = t; idx < 1024; idx += 256) {
            int k = idx >> 4, c4 = (idx & 15) << 2;
            *(float4*)&Bs[k][c4] = *(const float4*)&B0[(size_t)(kc + k) * 64 + c4];
        }
        __syncthreads();

        #pragma unroll 8
        for (int k = 0; k < 64; ++k) {
            float4 av = *(const float4*)&As[k][ty * 4];
            float4 bv = *(const float4*)&Bs[k][tx * 4];
            float ar[4] = {av.x, av.y, av.z, av.w};
            float br[4] = {bv.x, bv.y, bv.z, bv.w};
            #pragma unroll
            for (int i = 0; i < 4; ++i)
                #pragma unroll
                for (int j = 0; j < 4; ++j)
                    acc[i][j] = fmaf(ar[i], br[j], acc[i][j]);
        }
        __syncthreads();
    }

    float bb[4];
    {
        const float* bp = bias + tx * 4;
        bb[0] = bp[0]; bb[1] = bp[1]; bb[2] = bp[2]; bb[3] = bp[3];
    }
    #pragma unroll
    for (int i = 0; i < 4; ++i) {
        int gr = row0 + ty * 4 + i;
        if (gr >= M) continue;
        float v0 = acc[i][0] + bb[0], v1 = acc[i][1] + bb[1];
        float v2 = acc[i][2] + bb[2], v3 = acc[i][3] + bb[3];
        *(float4*)&C[(size_t)gr * 64 + tx * 4] = make_float4(v0, v1, v2, v3);
        ushort4 h;
        h.x = f32_bf16_rn(v0); h.y = f32_bf16_rn(v1);
        h.z = f32_bf16_rn(v2); h.w = f32_bf16_rn(v3);
        *(ushort4*)&Cb[(size_t)gr * 64 + tx * 4] = h;
    }
}

// ---------------------------------------------------------------------------
// zgather v6: one wave per dst node, 8-deep pipelined full-range walk,
// wave-uniform segment flushes. bf16 features in, bf16 Z out.
// ---------------------------------------------------------------------------
__launch_bounds__(256)
__global__ void zgather(const int* __restrict__ offs5,
                        const unsigned long long* __restrict__ epack,
                        const ushort_t* __restrict__ Eb,
                        ushort_t* __restrict__ Zb16, float* __restrict__ S)
{
    int wid = (blockIdx.x * 256 + threadIdx.x) >> 6;
    int lane = threadIdx.x & 63;
    if (wid >= NN) return;
    const int b = wid * RREL;

    int p    = offs5[b];
    int n1   = offs5[b + 1];
    int n2   = offs5[b + 2];
    int n3   = offs5[b + 3];
    int n4   = offs5[b + 4];
    int pend = offs5[b + 5];

    ushort_t* zr = Zb16 + (size_t)wid * 320 + lane;
    const int INFP = 0x7fffffff;

    int r = 0;
    float zA = 0.f, zB = 0.f, zC = 0.f, zD = 0.f;
    float sA = 0.f, sB = 0.f, sC = 0.f, sD = 0.f;

#define WVAL(q) __uint_as_float((unsigned)((q) >> 32))
#define SRCI(q) ((unsigned)(q) & 0xFFFFFFFFu)

#define FLUSH_CHECK(pe)                                                     \
    while (r < 4 && (pe) == n1) {                                           \
        zr[(size_t)(r << 6)] = f32_bf16_rn(zA + zB + zC + zD);              \
        if (lane == 0) S[b + r] = sA + sB + sC + sD;                        \
        zA = zB = zC = zD = 0.f; sA = sB = sC = sD = 0.f;                   \
        ++r; n1 = n2; n2 = n3; n3 = n4; n4 = INFP;                          \
    }

    for (; p + 8 <= pend; p += 8) {
        unsigned long long q0 = epack[p + 0];
        unsigned long long q1 = epack[p + 1];
        unsigned long long q2 = epack[p + 2];
        unsigned long long q3 = epack[p + 3];
        unsigned long long q4 = epack[p + 4];
        unsigned long long q5 = epack[p + 5];
        unsigned long long q6 = epack[p + 6];
        unsigned long long q7 = epack[p + 7];
        float v0 = bf16_f32(Eb[(size_t)SRCI(q0) * 64 + lane]);
        float v1 = bf16_f32(Eb[(size_t)SRCI(q1) * 64 + lane]);
        float v2 = bf16_f32(Eb[(size_t)SRCI(q2) * 64 + lane]);
        float v3 = bf16_f32(Eb[(size_t)SRCI(q3) * 64 + lane]);
        float v4 = bf16_f32(Eb[(size_t)SRCI(q4) * 64 + lane]);
        float v5 = bf16_f32(Eb[(size_t)SRCI(q5) * 64 + lane]);
        float v6 = bf16_f32(Eb[(size_t)SRCI(q6) * 64 + lane]);
        float v7 = bf16_f32(Eb[(size_t)SRCI(q7) * 64 + lane]);

        FLUSH_CHECK(p + 0);
        zA = fmaf(WVAL(q0), v0, zA); sA += WVAL(q0);
        FLUSH_CHECK(p + 1);
        zB = fmaf(WVAL(q1), v1, zB); sB += WVAL(q1);
        FLUSH_CHECK(p + 2);
        zC = fmaf(WVAL(q2), v2, zC); sC += WVAL(q2);
        FLUSH_CHECK(p + 3);
        zD = fmaf(WVAL(q3), v3, zD); sD += WVAL(q3);
        FLUSH_CHECK(p + 4);
        zA = fmaf(WVAL(q4), v4, zA); sA += WVAL(q4);
        FLUSH_CHECK(p + 5);
        zB = fmaf(WVAL(q5), v5, zB); sB += WVAL(q5);
        FLUSH_CHECK(p + 6);
        zC = fmaf(WVAL(q6), v6, zC); sC += WVAL(q6);
        FLUSH_CHECK(p + 7);
        zD = fmaf(WVAL(q7), v7, zD); sD += WVAL(q7);
    }
    for (; p < pend; ++p) {
        unsigned long long q = epack[p];
        float v = bf16_f32(Eb[(size_t)SRCI(q) * 64 + lane]);
        FLUSH_CHECK(p);
        zA = fmaf(WVAL(q), v, zA);
        sA += WVAL(q);
    }
    while (r < RREL) {
        zr[(size_t)(r << 6)] = f32_bf16_rn(zA + zB + zC + zD);
        if (lane == 0) S[b + r] = sA + sB + sC + sD;
        zA = zB = zC = zD = 0.f; sA = sB = sC = sD = 0.f;
        ++r;
    }
#undef FLUSH_CHECK
#undef WVAL
#undef SRCI
}

// ---------------------------------------------------------------------------
// prep_wfrag: relW [R][128][64] f32 -> split-bf16 MFMA fragments.
// ---------------------------------------------------------------------------
__launch_bounds__(256)
__global__ void prep_wfrag(const float* __restrict__ rel1_W, const float* __restrict__ rel2_W,
                           short8* __restrict__ wf1, short8* __restrict__ wf2)
{
    int bid = blockIdx.x;
    int layer = bid / 10, c = bid % 10;
    const float* relW = layer ? rel2_W : rel1_W;
    short8* wf = layer ? wf2 : wf1;
    int t = threadIdx.x;
    for (int sl = t; sl < 512; sl += 256) {
        int rid = sl >> 6, lane = sl & 63;
        int s = rid >> 2, nf = rid & 3;
        int g = lane >> 4, lc = lane & 15;
        int r = (c < 5) ? c : c - 5;
        const float* W = relW + (size_t)r * 8192 + ((c < 5) ? 0 : 4096);
        float v[8];
        #pragma unroll
        for (int j = 0; j < 8; ++j)
            v[j] = W[(size_t)(s * 32 + g * 8 + j) * 64 + nf * 16 + lc];
        float4 q0 = make_float4(v[0], v[1], v[2], v[3]);
        float4 q1 = make_float4(v[4], v[5], v[6], v[7]);
        short8 hi, lo;
        split8v(q0, q1, hi, lo);
        size_t slot = (size_t)c * 1024 + (size_t)((s * 4 + nf) * 64 + lane) * 2;
        wf[slot]     = hi;
        wf[slot + 1] = lo;
    }
}

// ---------------------------------------------------------------------------
// zgemm_mfma v3: 2-phase LDS pipeline; Z consumed as bf16 fragments directly
// (no split, 2 MFMA per (s,nf)); bot chunks keep full 3-product split.
// ---------------------------------------------------------------------------
__launch_bounds__(512)
__global__ void zgemm_mfma(const ushort_t* __restrict__ Zb16,
                           const float* __restrict__ Eprev,
                           const short8* __restrict__ wf,
                           const float* __restrict__ relb,
                           const float* __restrict__ S,
                           float* __restrict__ Enext, ushort_t* __restrict__ Enb, int M)
{
    __shared__ short8 wlds[2][1024];   // 2 x 16 KB

    const int t = threadIdx.x;
    const int wid = t >> 6, lane = t & 63;
    const int lc = lane & 15, lg = lane >> 4;
    const int row0 = blockIdx.x * 128 + wid * 16;

    const int nA = row0 + lc;
    const bool okA = (nA < M);
    const int nodeA = okA ? nA : 0;

    const int sq = t >> 6, sl = t & 63;
    const int wrA = (sq * 2 + 0) * 64 + sl;
    const int wrB = (sq * 2 + 1) * 64 + sl;

    short8 eh[2], el[2];
    #pragma unroll
    for (int s = 0; s < 2; ++s) {
        const float* p = &Eprev[(size_t)nodeA * 64 + s * 32 + lg * 8];
        float4 q0 = okA ? *(const float4*)p       : make_float4(0,0,0,0);
        float4 q1 = okA ? *(const float4*)(p + 4) : make_float4(0,0,0,0);
        split8v(q0, q1, eh[s], el[s]);
    }

    float sD[4][RREL];
    #pragma unroll
    for (int i = 0; i < 4; ++i) {
        int nd = row0 + lg * 4 + i;
        int ns = (nd < M) ? nd : 0;
        #pragma unroll
        for (int r = 0; r < RREL; ++r)
            sD[i][r] = S[(size_t)ns * RREL + r];
    }

    {
        const short8* wp = wf + (size_t)t * 2;
        short8 sa = wp[0], sb = wp[1];
        wlds[0][wrA] = sa; wlds[0][wrB] = sb;
    }
    // prefetch A for phase 0 (Z chunk 0, bf16 frags directly)
    short8 az0, az1;
    {
        const ushort_t* zb = &Zb16[(size_t)nodeA * 320 + lg * 8];
        az0 = okA ? *(const short8*)(zb)      : zero8();
        az1 = okA ? *(const short8*)(zb + 32) : zero8();
    }
    __syncthreads();

    f32x4 acc[4];
    #pragma unroll
    for (int nf = 0; nf < 4; ++nf) acc[nf] = (f32x4){0.f, 0.f, 0.f, 0.f};

    short8 sreg_a, sreg_b;
    short8 pz0, pz1;

    #pragma unroll
    for (int c = 0; c < 10; ++c) {
        const int cb = c & 1;
        if (c < 9) {
            const short8* wp = wf + (size_t)(c + 1) * 1024 + (size_t)t * 2;
            sreg_a = wp[0]; sreg_b = wp[1];
        }
        if (c < 4) {
            const ushort_t* zb = &Zb16[(size_t)nodeA * 320 + (c + 1) * 64 + lg * 8];
            pz0 = okA ? *(const short8*)(zb)      : zero8();
            pz1 = okA ? *(const short8*)(zb + 32) : zero8();
        }

        if (c < 5) {
            // Z chunk: A is bf16 (no lo part) -> 2 MFMA per (s,nf)
            #pragma unroll
            for (int s = 0; s < 2; ++s) {
                short8 Az = (s == 0) ? az0 : az1;
                #pragma unroll
                for (int nf = 0; nf < 4; ++nf) {
                    short8 bh = wlds[cb][((s * 4 + nf) * 2 + 0) * 64 + lane];
                    short8 bl = wlds[cb][((s * 4 + nf) * 2 + 1) * 64 + lane];
                    acc[nf] = __builtin_amdgcn_mfma_f32_16x16x32_bf16(Az, bh, acc[nf], 0, 0, 0);
                    acc[nf] = __builtin_amdgcn_mfma_f32_16x16x32_bf16(Az, bl, acc[nf], 0, 0, 0);
                }
            }
        } else {
            f32x4 tmp[4];
            #pragma unroll
            for (int nf = 0; nf < 4; ++nf) tmp[nf] = (f32x4){0.f, 0.f, 0.f, 0.f};
            #pragma unroll
            for (int s = 0; s < 2; ++s)
                #pragma unroll
                for (int nf = 0; nf < 4; ++nf) {
                    short8 bh = wlds[cb][((s * 4 + nf) * 2 + 0) * 64 + lane];
                    short8 bl = wlds[cb][((s * 4 + nf) * 2 + 1) * 64 + lane];
                    tmp[nf] = __builtin_amdgcn_mfma_f32_16x16x32_bf16(eh[s], bh, tmp[nf], 0, 0, 0);
                    tmp[nf] = __builtin_amdgcn_mfma_f32_16x16x32_bf16(el[s], bh, tmp[nf], 0, 0, 0);
                    tmp[nf] = __builtin_amdgcn_mfma_f32_16x16x32_bf16(eh[s], bl, tmp[nf], 0, 0, 0);
                }
            const int r = c - 5;
            #pragma unroll
            for (int nf = 0; nf < 4; ++nf)
                #pragma unroll
                for (int i = 0; i < 4; ++i)
                    acc[nf][i] += sD[i][r] * tmp[nf][i];
        }

        if (c < 4) { az0 = pz0; az1 = pz1; }

        if (c < 9) {
            __syncthreads();
            wlds[cb ^ 1][wrA] = sreg_a;
            wlds[cb ^ 1][wrB] = sreg_b;
            __syncthreads();
        }
    }

    float bbv[4][RREL];
    #pragma unroll
    for (int nf = 0; nf < 4; ++nf)
        #pragma unroll
        for (int r = 0; r < RREL; ++r)
            bbv[nf][r] = relb[r * 64 + nf * 16 + lc];

    #pragma unroll
    for (int i = 0; i < 4; ++i) {
        int nd = row0 + lg * 4 + i;
        if (nd >= M) continue;
        #pragma unroll
        for (int nf = 0; nf < 4; ++nf) {
            float v = acc[nf][i];
            #pragma unroll
            for (int r = 0; r < RREL; ++r)
                v += sD[i][r] * bbv[nf][r];
            Enext[(size_t)nd * 64 + nf * 16 + lc] = v;
            if (Enb) Enb[(size_t)nd * 64 + nf * 16 + lc] = f32_bf16_rn(v);
        }
    }
}

// ---------------------------------------------------------------------------
// Fused output head: out = sum_s lrelu(Es @ Ws + bs)
// ---------------------------------------------------------------------------
__launch_bounds__(256)
__global__ void head_fused(const float* __restrict__ E0, const float* __restrict__ E1,
                           const float* __restrict__ E2,
                           const float* __restrict__ W0, const float* __restrict__ W1,
                           const float* __restrict__ W2,
                           const float* __restrict__ b0, const float* __restrict__ b1,
                           const float* __restrict__ b2,
                           float* __restrict__ out, int M)
{
    __shared__ float As[64][68];
    __shared__ float Bs[64][64];
    const int row0 = blockIdx.x * 64;
    const int t = threadIdx.x;
    const int tx = t & 15, ty = t >> 4;

    const float* Es[3] = {E0, E1, E2};
    const float* Ws[3] = {W0, W1, W2};
    const float* bs[3] = {b0, b1, b2};

    float acc[4][4] = {};

    #pragma unroll
    for (int s = 0; s < 3; ++s) {
        __syncthreads();
        {
            int arow = t >> 4, akk = (t & 15) << 2;
            #pragma unroll
            for (int rp = 0; rp < 64; rp += 16) {
                int r = rp + arow, gr = row0 + r;
                float4 v = make_float4(0.f, 0.f, 0.f, 0.f);
                if (gr < M) v = *(const float4*)&Es[s][(size_t)gr * 64 + akk];
                As[akk + 0][r] = v.x; As[akk + 1][r] = v.y;
                As[akk + 2][r] = v.z; As[akk + 3][r] = v.w;
            }
        }
        #pragma unroll
        for (int idx = t; idx < 1024; idx += 256) {
            int k = idx >> 4, c4 = (idx & 15) << 2;
            *(float4*)&Bs[k][c4] = *(const float4*)&Ws[s][(size_t)k * 64 + c4];
        }
        __syncthreads();

        float tmp[4][4] = {};
        #pragma unroll 8
        for (int k = 0; k < 64; ++k) {
            float4 av = *(const float4*)&As[k][ty * 4];
            float4 bv = *(const float4*)&Bs[k][tx * 4];
            float ar[4] = {av.x, av.y, av.z, av.w};
            float br[4] = {bv.x, bv.y, bv.z, bv.w};
            #pragma unroll
            for (int i = 0; i < 4; ++i)
                #pragma unroll
                for (int j = 0; j < 4; ++j)
                    tmp[i][j] = fmaf(ar[i], br[j], tmp[i][j]);
        }
        float bb[4];
        {
            const float* bp = bs[s] + tx * 4;
            bb[0] = bp[0]; bb[1] = bp[1]; bb[2] = bp[2]; bb[3] = bp[3];
        }
        #pragma unroll
        for (int i = 0; i < 4; ++i)
            #pragma unroll
            for (int j = 0; j < 4; ++j)
                acc[i][j] += lrelu(tmp[i][j] + bb[j]);
    }

    #pragma unroll
    for (int i = 0; i < 4; ++i) {
        int gr = row0 + ty * 4 + i;
        if (gr >= M) continue;
        *(float4*)&out[(size_t)gr * 64 + tx * 4] =
            make_float4(acc[i][0], acc[i][1], acc[i][2], acc[i][3]);
    }
}

// ---------------------------------------------------------------------------
// CSR build over (dst,type) keys
// ---------------------------------------------------------------------------
__launch_bounds__(256)
__global__ void deg5_hist(const int* __restrict__ dst, const int* __restrict__ etype,
                          int* __restrict__ deg5, int* __restrict__ slot5)
{
    int e = blockIdx.x * 256 + threadIdx.x;
    if (e < NE) slot5[e] = atomicAdd(&deg5[dst[e] * RREL + etype[e]], 1);
}

__launch_bounds__(256)
__global__ void b1_reduce(const int* __restrict__ deg5, int* __restrict__ b1)
{
    __shared__ int sh[256];
    int i = blockIdx.x * 256 + threadIdx.x;
    sh[threadIdx.x] = (i < NR) ? deg5[i] : 0;
    __syncthreads();
    for (int s = 128; s > 0; s >>= 1) {
        if (threadIdx.x < s) sh[threadIdx.x] += sh[threadIdx.x + s];
        __syncthreads();
    }
    if (threadIdx.x == 0) b1[blockIdx.x] = sh[0];
}

__launch_bounds__(256)
__global__ void scan_seq(int* __restrict__ b1, int n)
{
    __shared__ int sh[256];
    __shared__ int carry;
    if (threadIdx.x == 0) carry = 0;
    __syncthreads();
    for (int base = 0; base < n; base += 256) {
        int i = base + threadIdx.x;
        int v = (i < n) ? b1[i] : 0;
        sh[threadIdx.x] = v;
        __syncthreads();
        for (int off = 1; off < 256; off <<= 1) {
            int x = (threadIdx.x >= off) ? sh[threadIdx.x - off] : 0;
            __syncthreads();
            sh[threadIdx.x] += x;
            __syncthreads();
        }
        int excl = sh[threadIdx.x] - v + carry;
        if (i < n) b1[i] = excl;
        __syncthreads();
        if (threadIdx.x == 255) carry = excl + v;
        __syncthreads();
    }
}

__launch_bounds__(256)
__global__ void offs5_final(const int* __restrict__ deg5, const int* __restrict__ b1,
                            int* __restrict__ offs5)
{
    __shared__ int sh[256];
    int t = threadIdx.x;
    int i = blockIdx.x * 256 + t;
    int v = (i < NR) ? deg5[i] : 0;
    sh[t] = v;
    __syncthreads();
    for (int off = 1; off < 256; off <<= 1) {
        int x = (t >= off) ? sh[t - off] : 0;
        __syncthreads();
        sh[t] += x;
        __syncthreads();
    }
    int excl = sh[t] - v + b1[blockIdx.x];
    if (i <= NR) offs5[i] = excl;
}

// scatter: epack[offs5[dst*5+r] + slot5[e]] = {w, src} packed u64
__launch_bounds__(256)
__global__ void scatter_pass(const int* __restrict__ src, const int* __restrict__ dst,
                             const int* __restrict__ etype,
                             const float* __restrict__ etime,
                             const float* __restrict__ beta,
                             const float* __restrict__ lambda_p,
                             const int* __restrict__ slot5, const int* __restrict__ offs5,
                             unsigned long long* __restrict__ epack)
{
    int e = blockIdx.x * 256 + threadIdx.x;
    if (e >= NE) return;
    float b[12];
    #pragma unroll
    for (int j = 0; j < 12; ++j) b[j] = beta[j];
    const float* et = etime + (size_t)e * 12;
    float4 v0 = *(const float4*)(et);
    float4 v1 = *(const float4*)(et + 4);
    float4 v2 = *(const float4*)(et + 8);
    float logit = v0.x*b[0] + v0.y*b[1] + v0.z*b[2] + v0.w*b[3]
                + v1.x*b[4] + v1.y*b[5] + v1.z*b[6] + v1.w*b[7]
                + v2.x*b[8] + v2.y*b[9] + v2.z*b[10] + v2.w*b[11];
    float we = lambda_p[0] * expf(-logit);
    int p = offs5[dst[e] * RREL + etype[e]] + slot5[e];
    epack[p] = ((unsigned long long)__float_as_uint(we) << 32) | (unsigned)src[e];
}

// ---------------------------------------------------------------------------
extern "C" void kernel_launch(void* const* d_in, const int* in_sizes, int n_in,
                              void* d_out, int out_size, void* d_ws, size_t ws_size,
                              hipStream_t stream)
{
    const float* x        = (const float*)d_in[0];
    const int*   eidx     = (const int*)d_in[1];
    const int*   etype    = (const int*)d_in[2];
    const float* etime    = (const float*)d_in[3];
    const float* lambda_p = (const float*)d_in[4];
    const float* beta     = (const float*)d_in[5];
    const float* field_W  = (const float*)d_in[6];
    const float* field_b  = (const float*)d_in[7];
    const float* rel1_W   = (const float*)d_in[8];
    const float* rel1_b   = (const float*)d_in[9];
    const float* rel2_W   = (const float*)d_in[10];
    const float* rel2_b   = (const float*)d_in[11];
    const float* out0_W   = (const float*)d_in[12];
    const float* out0_b   = (const float*)d_in[13];
    const float* out1_W   = (const float*)d_in[14];
    const float* out1_b   = (const float*)d_in[15];
    const float* out2_W   = (const float*)d_in[16];
    const float* out2_b   = (const float*)d_in[17];
    const int* src = eidx;
    const int* dst = eidx + NE;
    float* out = (float*)d_out;

    char* wsb = (char*)d_ws;
    size_t off = 0;
    auto carve = [&](size_t bytes) -> void* {
        void* p = (void*)(wsb + off);
        off += (bytes + 255) & ~(size_t)255;
        return p;
    };
    int*   deg5   = (int*)carve((size_t)NR * 4);            // 1 MB
    int*   offs5  = (int*)carve((size_t)(NR + 1) * 4);      // 1 MB
    int*   b1     = (int*)carve((size_t)NB5 * 4);
    int*   slot5  = (int*)carve((size_t)NE * 4);            // 3.2 MB
    float* S      = (float*)carve((size_t)NR * 4);          // 1 MB
    unsigned long long* epack = (unsigned long long*)carve((size_t)NE * 8); // 6.4 MB
    float* e0     = (float*)carve((size_t)NN * 64 * 4);     // 12.8 MB
    float* e1     = (float*)carve((size_t)NN * 64 * 4);     // 12.8 MB
    float* e2     = (float*)carve((size_t)NN * 64 * 4);     // 12.8 MB
    ushort_t* e0b = (ushort_t*)carve((size_t)NN * 64 * 2);  // 6.4 MB bf16 shadow
    ushort_t* e1b = (ushort_t*)carve((size_t)NN * 64 * 2);  // 6.4 MB bf16 shadow
    ushort_t* Zb16 = (ushort_t*)carve((size_t)NN * 320 * 2); // 32 MB bf16 Z
    short8* wf1   = (short8*)carve((size_t)20 * 16384);     // 320 KB
    short8* wf2   = (short8*)carve((size_t)20 * 16384);     // 320 KB

    dim3 blk(256);
    const int NT64  = (NN + 63) / 64;       // 782
    const int NT128 = (NN + 127) / 128;     // 391
    const int EB = (NE + 255) / 256;
    const int GB = (NN * 64 + 255) / 256;   // one wave per node

    // ---- CSR build over (dst,type) + weight frag prep ----
    hipMemsetAsync(deg5, 0, (size_t)NR * 4, stream);
    deg5_hist<<<EB, blk, 0, stream>>>(dst, etype, deg5, slot5);
    prep_wfrag<<<20, blk, 0, stream>>>(rel1_W, rel2_W, wf1, wf2);
    b1_reduce<<<NB5, blk, 0, stream>>>(deg5, b1);
    scan_seq<<<1, blk, 0, stream>>>(b1, NB5);
    offs5_final<<<NB5, blk, 0, stream>>>(deg5, b1, offs5);
    scatter_pass<<<EB, blk, 0, stream>>>(src, dst, etype, etime, beta, lambda_p,
                                         slot5, offs5, epack);

    // ---- e0 = x @ field_W + field_b (+ bf16 shadow) ----
    gemm_tile<128><<<dim3(NT64), blk, 0, stream>>>(x, 128, field_W, field_b, e0, e0b, NN);

    // ---- layer 1 ----
    zgather<<<GB, blk, 0, stream>>>(offs5, epack, e0b, Zb16, S);
    zgemm_mfma<<<dim3(NT128), dim3(512), 0, stream>>>(Zb16, e0, wf1, rel1_b, S, e1, e1b, NN);

    // ---- layer 2 ----
    zgather<<<GB, blk, 0, stream>>>(offs5, epack, e1b, Zb16, S);
    zgemm_mfma<<<dim3(NT128), dim3(512), 0, stream>>>(Zb16, e1, wf2, rel2_b, S, e2, nullptr, NN);

    // ---- output head (single pass) ----
    head_fused<<<dim3(NT64), blk, 0, stream>>>(e0, e1, e2, out0_W, out1_W, out2_W,
                                               out0_b, out1_b, out2_b, out, NN);
}

// Round 15
// 215.630 us; speedup vs baseline: 1.4606x; 1.1969x over previous
//
#include <hip/hip_runtime.h>
#include <cstdint>
#include <cstddef>

#define NN 50000
#define NE 800000
#define RREL 5
#define NR (NN * RREL)                 // 250000 (dst,type) keys
#define NB5 ((NR + 255) / 256)         // 977

typedef __attribute__((ext_vector_type(8))) short short8;   // 8 bf16 (4 VGPRs)
typedef __attribute__((ext_vector_type(4))) float f32x4;
typedef unsigned short ushort_t;

static __device__ __forceinline__ float lrelu(float v) { return v > 0.f ? v : 0.01f * v; }

static __device__ __forceinline__ unsigned short f32_bf16_rn(float x) {
    unsigned u = __float_as_uint(x);
    return (unsigned short)((u + 0x7FFFu + ((u >> 16) & 1u)) >> 16);
}
static __device__ __forceinline__ float bf16_f32(unsigned short h) {
    return __uint_as_float(((unsigned)h) << 16);
}

// split 8 f32 (two float4) into bf16 hi + lo (x ~= hi + lo)
static __device__ __forceinline__ void split8v(float4 q0, float4 q1, short8& hi, short8& lo) {
    float v[8] = {q0.x, q0.y, q0.z, q0.w, q1.x, q1.y, q1.z, q1.w};
    #pragma unroll
    for (int j = 0; j < 8; ++j) {
        unsigned short h = f32_bf16_rn(v[j]);
        float hf = __uint_as_float(((unsigned)h) << 16);
        unsigned short l = f32_bf16_rn(v[j] - hf);
        hi[j] = (short)h; lo[j] = (short)l;
    }
}

static __device__ __forceinline__ short8 zero8() {
    short8 z = {0, 0, 0, 0, 0, 0, 0, 0};
    return z;
}

// ---------------------------------------------------------------------------
// lin_mfma: e0 = x @ field_W + field_b  (K=128), split-bf16 A (2 products),
// hi-only W frags pre-staged in 16 KB LDS. 512 thr, 128 rows/block.
// Emits f32 + bf16 shadow.
// ---------------------------------------------------------------------------
__launch_bounds__(512)
__global__ void lin_mfma(const float* __restrict__ X,
                         const short8* __restrict__ ff,   // [16][64] hi frags
                         const float* __restrict__ bias,
                         float* __restrict__ C, ushort_t* __restrict__ Cb, int M)
{
    __shared__ short8 wl[16 * 64];   // 16 KB

    const int t = threadIdx.x;
    const int wid = t >> 6, lane = t & 63;
    const int lc = lane & 15, lg = lane >> 4;
    const int row0 = blockIdx.x * 128 + wid * 16;

    const int nA = row0 + lc;
    const bool okA = (nA < M);
    const int nodeA = okA ? nA : 0;

    // stage W frags (1024 entries, 2 per thread)
    wl[t] = ff[t];
    wl[t + 512] = ff[t + 512];

    // A: x[node], K=128 -> 4 slices of 32, split hi/lo
    short8 ah[4], al[4];
    #pragma unroll
    for (int s = 0; s < 4; ++s) {
        const float* p = &X[(size_t)nodeA * 128 + s * 32 + lg * 8];
        float4 q0 = okA ? *(const float4*)p       : make_float4(0,0,0,0);
        float4 q1 = okA ? *(const float4*)(p + 4) : make_float4(0,0,0,0);
        split8v(q0, q1, ah[s], al[s]);
    }
    __syncthreads();

    f32x4 acc[4];
    #pragma unroll
    for (int nf = 0; nf < 4; ++nf) acc[nf] = (f32x4){0.f, 0.f, 0.f, 0.f};

    #pragma unroll
    for (int s = 0; s < 4; ++s)
        #pragma unroll
        for (int nf = 0; nf < 4; ++nf) {
            short8 bh = wl[(s * 4 + nf) * 64 + lane];
            acc[nf] = __builtin_amdgcn_mfma_f32_16x16x32_bf16(ah[s], bh, acc[nf], 0, 0, 0);
            acc[nf] = __builtin_amdgcn_mfma_f32_16x16x32_bf16(al[s], bh, acc[nf], 0, 0, 0);
        }

    float bb[4];
    #pragma unroll
    for (int nf = 0; nf < 4; ++nf) bb[nf] = bias[nf * 16 + lc];

    #pragma unroll
    for (int i = 0; i < 4; ++i) {
        int nd = row0 + lg * 4 + i;
        if (nd >= M) continue;
        #pragma unroll
        for (int nf = 0; nf < 4; ++nf) {
            float v = acc[nf][i] + bb[nf];
            C[(size_t)nd * 64 + nf * 16 + lc] = v;
            Cb[(size_t)nd * 64 + nf * 16 + lc] = f32_bf16_rn(v);
        }
    }
}

// ---------------------------------------------------------------------------
// head_mfma: out = sum_src lrelu(E_src @ W_src + b_src).
// W hi-only frags (24 KB LDS), A split-2, per-source lrelu into f32 acc.
// ---------------------------------------------------------------------------
__launch_bounds__(512)
__global__ void head_mfma(const float* __restrict__ E0, const float* __restrict__ E1,
                          const float* __restrict__ E2,
                          const short8* __restrict__ hf,   // [3][8][64] hi frags
                          const float* __restrict__ b0, const float* __restrict__ b1,
                          const float* __restrict__ b2,
                          float* __restrict__ out, int M)
{
    __shared__ short8 wl[24 * 64];   // 24 KB

    const int t = threadIdx.x;
    const int wid = t >> 6, lane = t & 63;
    const int lc = lane & 15, lg = lane >> 4;
    const int row0 = blockIdx.x * 128 + wid * 16;

    const int nA = row0 + lc;
    const bool okA = (nA < M);
    const int nodeA = okA ? nA : 0;

    wl[t] = hf[t];
    wl[t + 512] = hf[t + 512];
    wl[t + 1024] = hf[t + 1024];

    const float* Es[3] = {E0, E1, E2};
    const float* bs[3] = {b0, b1, b2};

    float facc[4][4] = {};   // [nf][i]
    __syncthreads();

    #pragma unroll
    for (int src = 0; src < 3; ++src) {
        short8 ah[2], al[2];
        #pragma unroll
        for (int s = 0; s < 2; ++s) {
            const float* p = &Es[src][(size_t)nodeA * 64 + s * 32 + lg * 8];
            float4 q0 = okA ? *(const float4*)p       : make_float4(0,0,0,0);
            float4 q1 = okA ? *(const float4*)(p + 4) : make_float4(0,0,0,0);
            split8v(q0, q1, ah[s], al[s]);
        }
        f32x4 acc[4];
        #pragma unroll
        for (int nf = 0; nf < 4; ++nf) acc[nf] = (f32x4){0.f, 0.f, 0.f, 0.f};
        #pragma unroll
        for (int s = 0; s < 2; ++s)
            #pragma unroll
            for (int nf = 0; nf < 4; ++nf) {
                short8 bh = wl[((src * 2 + s) * 4 + nf) * 64 + lane];
                acc[nf] = __builtin_amdgcn_mfma_f32_16x16x32_bf16(ah[s], bh, acc[nf], 0, 0, 0);
                acc[nf] = __builtin_amdgcn_mfma_f32_16x16x32_bf16(al[s], bh, acc[nf], 0, 0, 0);
            }
        float bb[4];
        #pragma unroll
        for (int nf = 0; nf < 4; ++nf) bb[nf] = bs[src][nf * 16 + lc];
        #pragma unroll
        for (int nf = 0; nf < 4; ++nf)
            #pragma unroll
            for (int i = 0; i < 4; ++i)
                facc[nf][i] += lrelu(acc[nf][i] + bb[nf]);
    }

    #pragma unroll
    for (int i = 0; i < 4; ++i) {
        int nd = row0 + lg * 4 + i;
        if (nd >= M) continue;
        #pragma unroll
        for (int nf = 0; nf < 4; ++nf)
            out[(size_t)nd * 64 + nf * 16 + lc] = facc[nf][i];
    }
}

// ---------------------------------------------------------------------------
// zgather v7: 8-deep pipelined walk; boundaries scalarized (readfirstlane)
// so FLUSH_CHECK runs on the scalar pipe. bf16 features in, bf16 Z out.
// ---------------------------------------------------------------------------
__launch_bounds__(256)
__global__ void zgather(const int* __restrict__ offs5,
                        const unsigned long long* __restrict__ epack,
                        const ushort_t* __restrict__ Eb,
                        ushort_t* __restrict__ Zb16, float* __restrict__ S)
{
    int wid = (blockIdx.x * 256 + threadIdx.x) >> 6;
    int lane = threadIdx.x & 63;
    if (wid >= NN) return;
    const int b = wid * RREL;

    int p    = __builtin_amdgcn_readfirstlane(offs5[b]);
    int n1   = __builtin_amdgcn_readfirstlane(offs5[b + 1]);
    int n2   = __builtin_amdgcn_readfirstlane(offs5[b + 2]);
    int n3   = __builtin_amdgcn_readfirstlane(offs5[b + 3]);
    int n4   = __builtin_amdgcn_readfirstlane(offs5[b + 4]);
    int pend = __builtin_amdgcn_readfirstlane(offs5[b + 5]);

    ushort_t* zr = Zb16 + (size_t)wid * 320 + lane;
    const int INFP = 0x7fffffff;

    int r = 0;
    float zA = 0.f, zB = 0.f, zC = 0.f, zD = 0.f;
    float sA = 0.f, sB = 0.f, sC = 0.f, sD = 0.f;

#define WVAL(q) __uint_as_float((unsigned)((q) >> 32))
#define SRCI(q) ((unsigned)(q) & 0xFFFFFFFFu)

#define FLUSH_CHECK(pe)                                                     \
    while (r < 4 && (pe) == n1) {                                           \
        zr[(size_t)(r << 6)] = f32_bf16_rn(zA + zB + zC + zD);              \
        if (lane == 0) S[b + r] = sA + sB + sC + sD;                        \
        zA = zB = zC = zD = 0.f; sA = sB = sC = sD = 0.f;                   \
        ++r; n1 = n2; n2 = n3; n3 = n4; n4 = INFP;                          \
    }

    for (; p + 8 <= pend; p += 8) {
        unsigned long long q0 = epack[p + 0];
        unsigned long long q1 = epack[p + 1];
        unsigned long long q2 = epack[p + 2];
        unsigned long long q3 = epack[p + 3];
        unsigned long long q4 = epack[p + 4];
        unsigned long long q5 = epack[p + 5];
        unsigned long long q6 = epack[p + 6];
        unsigned long long q7 = epack[p + 7];
        float v0 = bf16_f32(Eb[(size_t)SRCI(q0) * 64 + lane]);
        float v1 = bf16_f32(Eb[(size_t)SRCI(q1) * 64 + lane]);
        float v2 = bf16_f32(Eb[(size_t)SRCI(q2) * 64 + lane]);
        float v3 = bf16_f32(Eb[(size_t)SRCI(q3) * 64 + lane]);
        float v4 = bf16_f32(Eb[(size_t)SRCI(q4) * 64 + lane]);
        float v5 = bf16_f32(Eb[(size_t)SRCI(q5) * 64 + lane]);
        float v6 = bf16_f32(Eb[(size_t)SRCI(q6) * 64 + lane]);
        float v7 = bf16_f32(Eb[(size_t)SRCI(q7) * 64 + lane]);

        FLUSH_CHECK(p + 0);
        zA = fmaf(WVAL(q0), v0, zA); sA += WVAL(q0);
        FLUSH_CHECK(p + 1);
        zB = fmaf(WVAL(q1), v1, zB); sB += WVAL(q1);
        FLUSH_CHECK(p + 2);
        zC = fmaf(WVAL(q2), v2, zC); sC += WVAL(q2);
        FLUSH_CHECK(p + 3);
        zD = fmaf(WVAL(q3), v3, zD); sD += WVAL(q3);
        FLUSH_CHECK(p + 4);
        zA = fmaf(WVAL(q4), v4, zA); sA += WVAL(q4);
        FLUSH_CHECK(p + 5);
        zB = fmaf(WVAL(q5), v5, zB); sB += WVAL(q5);
        FLUSH_CHECK(p + 6);
        zC = fmaf(WVAL(q6), v6, zC); sC += WVAL(q6);
        FLUSH_CHECK(p + 7);
        zD = fmaf(WVAL(q7), v7, zD); sD += WVAL(q7);
    }
    for (; p < pend; ++p) {
        unsigned long long q = epack[p];
        float v = bf16_f32(Eb[(size_t)SRCI(q) * 64 + lane]);
        FLUSH_CHECK(p);
        zA = fmaf(WVAL(q), v, zA);
        sA += WVAL(q);
    }
    while (r < RREL) {
        zr[(size_t)(r << 6)] = f32_bf16_rn(zA + zB + zC + zD);
        if (lane == 0) S[b + r] = sA + sB + sC + sD;
        zA = zB = zC = zD = 0.f; sA = sB = sC = sD = 0.f;
        ++r;
    }
#undef FLUSH_CHECK
#undef WVAL
#undef SRCI
}

// ---------------------------------------------------------------------------
// prep_wfrag: weight fragment prep.
//  bid 0..19 : rel1/rel2 chunks (hi+lo, as before)
//  bid 20..23: field_W K-slice frags (hi only) -> ff
//  bid 24..26: out{0,1,2}_W frags (hi only)    -> hf
// ---------------------------------------------------------------------------
__launch_bounds__(256)
__global__ void prep_wfrag(const float* __restrict__ rel1_W, const float* __restrict__ rel2_W,
                           const float* __restrict__ field_W,
                           const float* __restrict__ out0_W, const float* __restrict__ out1_W,
                           const float* __restrict__ out2_W,
                           short8* __restrict__ wf1, short8* __restrict__ wf2,
                           short8* __restrict__ ff, short8* __restrict__ hf)
{
    int bid = blockIdx.x;
    int t = threadIdx.x;

    if (bid < 20) {
        int layer = bid / 10, c = bid % 10;
        const float* relW = layer ? rel2_W : rel1_W;
        short8* wf = layer ? wf2 : wf1;
        for (int sl = t; sl < 512; sl += 256) {
            int rid = sl >> 6, lane = sl & 63;
            int s = rid >> 2, nf = rid & 3;
            int g = lane >> 4, lc = lane & 15;
            int r = (c < 5) ? c : c - 5;
            const float* W = relW + (size_t)r * 8192 + ((c < 5) ? 0 : 4096);
            float v[8];
            #pragma unroll
            for (int j = 0; j < 8; ++j)
                v[j] = W[(size_t)(s * 32 + g * 8 + j) * 64 + nf * 16 + lc];
            float4 q0 = make_float4(v[0], v[1], v[2], v[3]);
            float4 q1 = make_float4(v[4], v[5], v[6], v[7]);
            short8 hi, lo;
            split8v(q0, q1, hi, lo);
            size_t slot = (size_t)c * 1024 + (size_t)((s * 4 + nf) * 64 + lane) * 2;
            wf[slot]     = hi;
            wf[slot + 1] = lo;
        }
    } else if (bid < 24) {
        int s = bid - 20;             // K-slice 0..3
        for (int sl = t; sl < 256; sl += 256) {
            int nf = sl >> 6, lane = sl & 63;
            int g = lane >> 4, lc = lane & 15;
            float v[8];
            #pragma unroll
            for (int j = 0; j < 8; ++j)
                v[j] = field_W[(size_t)(s * 32 + g * 8 + j) * 64 + nf * 16 + lc];
            short8 hi;
            #pragma unroll
            for (int j = 0; j < 8; ++j) hi[j] = (short)f32_bf16_rn(v[j]);
            ff[(size_t)(s * 4 + nf) * 64 + lane] = hi;
        }
    } else {
        int hsrc = bid - 24;          // 0..2
        const float* W = (hsrc == 0) ? out0_W : (hsrc == 1) ? out1_W : out2_W;
        for (int sl = t; sl < 512; sl += 256) {
            int rid = sl >> 6, lane = sl & 63;
            int s = rid >> 2, nf = rid & 3;
            if (s >= 2) continue;     // only 8 slots (2 slices x 4 nf)
            int g = lane >> 4, lc = lane & 15;
            float v[8];
            #pragma unroll
            for (int j = 0; j < 8; ++j)
                v[j] = W[(size_t)(s * 32 + g * 8 + j) * 64 + nf * 16 + lc];
            short8 hi;
            #pragma unroll
            for (int j = 0; j < 8; ++j) hi[j] = (short)f32_bf16_rn(v[j]);
            hf[(size_t)((hsrc * 2 + s) * 4 + nf) * 64 + lane] = hi;
        }
    }
}

// ---------------------------------------------------------------------------
// zgemm_mfma v3: 2-phase LDS pipeline; Z bf16 direct fragments (unchanged).
// ---------------------------------------------------------------------------
__launch_bounds__(512)
__global__ void zgemm_mfma(const ushort_t* __restrict__ Zb16,
                           const float* __restrict__ Eprev,
                           const short8* __restrict__ wf,
                           const float* __restrict__ relb,
                           const float* __restrict__ S,
                           float* __restrict__ Enext, ushort_t* __restrict__ Enb, int M)
{
    __shared__ short8 wlds[2][1024];   // 2 x 16 KB

    const int t = threadIdx.x;
    const int wid = t >> 6, lane = t & 63;
    const int lc = lane & 15, lg = lane >> 4;
    const int row0 = blockIdx.x * 128 + wid * 16;

    const int nA = row0 + lc;
    const bool okA = (nA < M);
    const int nodeA = okA ? nA : 0;

    const int sq = t >> 6, sl = t & 63;
    const int wrA = (sq * 2 + 0) * 64 + sl;
    const int wrB = (sq * 2 + 1) * 64 + sl;

    short8 eh[2], el[2];
    #pragma unroll
    for (int s = 0; s < 2; ++s) {
        const float* p = &Eprev[(size_t)nodeA * 64 + s * 32 + lg * 8];
        float4 q0 = okA ? *(const float4*)p       : make_float4(0,0,0,0);
        float4 q1 = okA ? *(const float4*)(p + 4) : make_float4(0,0,0,0);
        split8v(q0, q1, eh[s], el[s]);
    }

    float sD[4][RREL];
    #pragma unroll
    for (int i = 0; i < 4; ++i) {
        int nd = row0 + lg * 4 + i;
        int ns = (nd < M) ? nd : 0;
        #pragma unroll
        for (int r = 0; r < RREL; ++r)
            sD[i][r] = S[(size_t)ns * RREL + r];
    }

    {
        const short8* wp = wf + (size_t)t * 2;
        short8 sa = wp[0], sb = wp[1];
        wlds[0][wrA] = sa; wlds[0][wrB] = sb;
    }
    short8 az0, az1;
    {
        const ushort_t* zb = &Zb16[(size_t)nodeA * 320 + lg * 8];
        az0 = okA ? *(const short8*)(zb)      : zero8();
        az1 = okA ? *(const short8*)(zb + 32) : zero8();
    }
    __syncthreads();

    f32x4 acc[4];
    #pragma unroll
    for (int nf = 0; nf < 4; ++nf) acc[nf] = (f32x4){0.f, 0.f, 0.f, 0.f};

    short8 sreg_a, sreg_b;
    short8 pz0, pz1;

    #pragma unroll
    for (int c = 0; c < 10; ++c) {
        const int cb = c & 1;
        if (c < 9) {
            const short8* wp = wf + (size_t)(c + 1) * 1024 + (size_t)t * 2;
            sreg_a = wp[0]; sreg_b = wp[1];
        }
        if (c < 4) {
            const ushort_t* zb = &Zb16[(size_t)nodeA * 320 + (c + 1) * 64 + lg * 8];
            pz0 = okA ? *(const short8*)(zb)      : zero8();
            pz1 = okA ? *(const short8*)(zb + 32) : zero8();
        }

        if (c < 5) {
            #pragma unroll
            for (int s = 0; s < 2; ++s) {
                short8 Az = (s == 0) ? az0 : az1;
                #pragma unroll
                for (int nf = 0; nf < 4; ++nf) {
                    short8 bh = wlds[cb][((s * 4 + nf) * 2 + 0) * 64 + lane];
                    short8 bl = wlds[cb][((s * 4 + nf) * 2 + 1) * 64 + lane];
                    acc[nf] = __builtin_amdgcn_mfma_f32_16x16x32_bf16(Az, bh, acc[nf], 0, 0, 0);
                    acc[nf] = __builtin_amdgcn_mfma_f32_16x16x32_bf16(Az, bl, acc[nf], 0, 0, 0);
                }
            }
        } else {
            f32x4 tmp[4];
            #pragma unroll
            for (int nf = 0; nf < 4; ++nf) tmp[nf] = (f32x4){0.f, 0.f, 0.f, 0.f};
            #pragma unroll
            for (int s = 0; s < 2; ++s)
                #pragma unroll
                for (int nf = 0; nf < 4; ++nf) {
                    short8 bh = wlds[cb][((s * 4 + nf) * 2 + 0) * 64 + lane];
                    short8 bl = wlds[cb][((s * 4 + nf) * 2 + 1) * 64 + lane];
                    tmp[nf] = __builtin_amdgcn_mfma_f32_16x16x32_bf16(eh[s], bh, tmp[nf], 0, 0, 0);
                    tmp[nf] = __builtin_amdgcn_mfma_f32_16x16x32_bf16(el[s], bh, tmp[nf], 0, 0, 0);
                    tmp[nf] = __builtin_amdgcn_mfma_f32_16x16x32_bf16(eh[s], bl, tmp[nf], 0, 0, 0);
                }
            const int r = c - 5;
            #pragma unroll
            for (int nf = 0; nf < 4; ++nf)
                #pragma unroll
                for (int i = 0; i < 4; ++i)
                    acc[nf][i] += sD[i][r] * tmp[nf][i];
        }

        if (c < 4) { az0 = pz0; az1 = pz1; }

        if (c < 9) {
            __syncthreads();
            wlds[cb ^ 1][wrA] = sreg_a;
            wlds[cb ^ 1][wrB] = sreg_b;
            __syncthreads();
        }
    }

    float bbv[4][RREL];
    #pragma unroll
    for (int nf = 0; nf < 4; ++nf)
        #pragma unroll
        for (int r = 0; r < RREL; ++r)
            bbv[nf][r] = relb[r * 64 + nf * 16 + lc];

    #pragma unroll
    for (int i = 0; i < 4; ++i) {
        int nd = row0 + lg * 4 + i;
        if (nd >= M) continue;
        #pragma unroll
        for (int nf = 0; nf < 4; ++nf) {
            float v = acc[nf][i];
            #pragma unroll
            for (int r = 0; r < RREL; ++r)
                v += sD[i][r] * bbv[nf][r];
            Enext[(size_t)nd * 64 + nf * 16 + lc] = v;
            if (Enb) Enb[(size_t)nd * 64 + nf * 16 + lc] = f32_bf16_rn(v);
        }
    }
}

// ---------------------------------------------------------------------------
// CSR build over (dst,type) keys
// ---------------------------------------------------------------------------
__launch_bounds__(256)
__global__ void deg5_hist(const int* __restrict__ dst, const int* __restrict__ etype,
                          int* __restrict__ deg5, int* __restrict__ slot5)
{
    int e = blockIdx.x * 256 + threadIdx.x;
    if (e < NE) slot5[e] = atomicAdd(&deg5[dst[e] * RREL + etype[e]], 1);
}

__launch_bounds__(256)
__global__ void b1_reduce(const int* __restrict__ deg5, int* __restrict__ b1)
{
    __shared__ int sh[256];
    int i = blockIdx.x * 256 + threadIdx.x;
    sh[threadIdx.x] = (i < NR) ? deg5[i] : 0;
    __syncthreads();
    for (int s = 128; s > 0; s >>= 1) {
        if (threadIdx.x < s) sh[threadIdx.x] += sh[threadIdx.x + s];
        __syncthreads();
    }
    if (threadIdx.x == 0) b1[blockIdx.x] = sh[0];
}

__launch_bounds__(256)
__global__ void scan_seq(int* __restrict__ b1, int n)
{
    __shared__ int sh[256];
    __shared__ int carry;
    if (threadIdx.x == 0) carry = 0;
    __syncthreads();
    for (int base = 0; base < n; base += 256) {
        int i = base + threadIdx.x;
        int v = (i < n) ? b1[i] : 0;
        sh[threadIdx.x] = v;
        __syncthreads();
        for (int off = 1; off < 256; off <<= 1) {
            int x = (threadIdx.x >= off) ? sh[threadIdx.x - off] : 0;
            __syncthreads();
            sh[threadIdx.x] += x;
            __syncthreads();
        }
        int excl = sh[threadIdx.x] - v + carry;
        if (i < n) b1[i] = excl;
        __syncthreads();
        if (threadIdx.x == 255) carry = excl + v;
        __syncthreads();
    }
}

__launch_bounds__(256)
__global__ void offs5_final(const int* __restrict__ deg5, const int* __restrict__ b1,
                            int* __restrict__ offs5)
{
    __shared__ int sh[256];
    int t = threadIdx.x;
    int i = blockIdx.x * 256 + t;
    int v = (i < NR) ? deg5[i] : 0;
    sh[t] = v;
    __syncthreads();
    for (int off = 1; off < 256; off <<= 1) {
        int x = (t >= off) ? sh[t - off] : 0;
        __syncthreads();
        sh[t] += x;
        __syncthreads();
    }
    int excl = sh[t] - v + b1[blockIdx.x];
    if (i <= NR) offs5[i] = excl;
}

// scatter: epack[offs5[dst*5+r] + slot5[e]] = {w, src} packed u64
__launch_bounds__(256)
__global__ void scatter_pass(const int* __restrict__ src, const int* __restrict__ dst,
                             const int* __restrict__ etype,
                             const float* __restrict__ etime,
                             const float* __restrict__ beta,
                             const float* __restrict__ lambda_p,
                             const int* __restrict__ slot5, const int* __restrict__ offs5,
                             unsigned long long* __restrict__ epack)
{
    int e = blockIdx.x * 256 + threadIdx.x;
    if (e >= NE) return;
    float b[12];
    #pragma unroll
    for (int j = 0; j < 12; ++j) b[j] = beta[j];
    const float* et = etime + (size_t)e * 12;
    float4 v0 = *(const float4*)(et);
    float4 v1 = *(const float4*)(et + 4);
    float4 v2 = *(const float4*)(et + 8);
    float logit = v0.x*b[0] + v0.y*b[1] + v0.z*b[2] + v0.w*b[3]
                + v1.x*b[4] + v1.y*b[5] + v1.z*b[6] + v1.w*b[7]
                + v2.x*b[8] + v2.y*b[9] + v2.z*b[10] + v2.w*b[11];
    float we = lambda_p[0] * expf(-logit);
    int p = offs5[dst[e] * RREL + etype[e]] + slot5[e];
    epack[p] = ((unsigned long long)__float_as_uint(we) << 32) | (unsigned)src[e];
}

// ---------------------------------------------------------------------------
extern "C" void kernel_launch(void* const* d_in, const int* in_sizes, int n_in,
                              void* d_out, int out_size, void* d_ws, size_t ws_size,
                              hipStream_t stream)
{
    const float* x        = (const float*)d_in[0];
    const int*   eidx     = (const int*)d_in[1];
    const int*   etype    = (const int*)d_in[2];
    const float* etime    = (const float*)d_in[3];
    const float* lambda_p = (const float*)d_in[4];
    const float* beta     = (const float*)d_in[5];
    const float* field_W  = (const float*)d_in[6];
    const float* field_b  = (const float*)d_in[7];
    const float* rel1_W   = (const float*)d_in[8];
    const float* rel1_b   = (const float*)d_in[9];
    const float* rel2_W   = (const float*)d_in[10];
    const float* rel2_b   = (const float*)d_in[11];
    const float* out0_W   = (const float*)d_in[12];
    const float* out0_b   = (const float*)d_in[13];
    const float* out1_W   = (const float*)d_in[14];
    const float* out1_b   = (const float*)d_in[15];
    const float* out2_W   = (const float*)d_in[16];
    const float* out2_b   = (const float*)d_in[17];
    const int* src = eidx;
    const int* dst = eidx + NE;
    float* out = (float*)d_out;

    char* wsb = (char*)d_ws;
    size_t off = 0;
    auto carve = [&](size_t bytes) -> void* {
        void* p = (void*)(wsb + off);
        off += (bytes + 255) & ~(size_t)255;
        return p;
    };
    int*   deg5   = (int*)carve((size_t)NR * 4);            // 1 MB
    int*   offs5  = (int*)carve((size_t)(NR + 1) * 4);      // 1 MB
    int*   b1     = (int*)carve((size_t)NB5 * 4);
    int*   slot5  = (int*)carve((size_t)NE * 4);            // 3.2 MB
    float* S      = (float*)carve((size_t)NR * 4);          // 1 MB
    unsigned long long* epack = (unsigned long long*)carve((size_t)NE * 8); // 6.4 MB
    float* e0     = (float*)carve((size_t)NN * 64 * 4);     // 12.8 MB
    float* e1     = (float*)carve((size_t)NN * 64 * 4);     // 12.8 MB
    float* e2     = (float*)carve((size_t)NN * 64 * 4);     // 12.8 MB
    ushort_t* e0b = (ushort_t*)carve((size_t)NN * 64 * 2);  // 6.4 MB bf16 shadow
    ushort_t* e1b = (ushort_t*)carve((size_t)NN * 64 * 2);  // 6.4 MB bf16 shadow
    ushort_t* Zb16 = (ushort_t*)carve((size_t)NN * 320 * 2); // 32 MB bf16 Z
    short8* wf1   = (short8*)carve((size_t)20 * 16384);     // 320 KB
    short8* wf2   = (short8*)carve((size_t)20 * 16384);     // 320 KB
    short8* ff    = (short8*)carve((size_t)16 * 64 * 16);   // 16 KB field frags
    short8* hf    = (short8*)carve((size_t)24 * 64 * 16);   // 24 KB head frags

    dim3 blk(256);
    const int NT128 = (NN + 127) / 128;     // 391
    const int EB = (NE + 255) / 256;
    const int GB = (NN * 64 + 255) / 256;   // one wave per node

    // ---- CSR build over (dst,type) + weight frag prep ----
    hipMemsetAsync(deg5, 0, (size_t)NR * 4, stream);
    deg5_hist<<<EB, blk, 0, stream>>>(dst, etype, deg5, slot5);
    prep_wfrag<<<27, blk, 0, stream>>>(rel1_W, rel2_W, field_W, out0_W, out1_W, out2_W,
                                       wf1, wf2, ff, hf);
    b1_reduce<<<NB5, blk, 0, stream>>>(deg5, b1);
    scan_seq<<<1, blk, 0, stream>>>(b1, NB5);
    offs5_final<<<NB5, blk, 0, stream>>>(deg5, b1, offs5);
    scatter_pass<<<EB, blk, 0, stream>>>(src, dst, etype, etime, beta, lambda_p,
                                         slot5, offs5, epack);

    // ---- e0 = x @ field_W + field_b (MFMA, + bf16 shadow) ----
    lin_mfma<<<dim3(NT128), dim3(512), 0, stream>>>(x, ff, field_b, e0, e0b, NN);

    // ---- layer 1 ----
    zgather<<<GB, blk, 0, stream>>>(offs5, epack, e0b, Zb16, S);
    zgemm_mfma<<<dim3(NT128), dim3(512), 0, stream>>>(Zb16, e0, wf1, rel1_b, S, e1, e1b, NN);

    // ---- layer 2 ----
    zgather<<<GB, blk, 0, stream>>>(offs5, epack, e1b, Zb16, S);
    zgemm_mfma<<<dim3(NT128), dim3(512), 0, stream>>>(Zb16, e1, wf2, rel2_b, S, e2, nullptr, NN);

    // ---- output head (MFMA, single pass) ----
    head_mfma<<<dim3(NT128), dim3(512), 0, stream>>>(e0, e1, e2, hf,
                                                     out0_b, out1_b, out2_b, out, NN);
}

// Round 16
// 215.494 us; speedup vs baseline: 1.4615x; 1.0006x over previous
//
#include <hip/hip_runtime.h>
#include <cstdint>
#include <cstddef>

#define NN 50000
#define NE 800000
#define RREL 5
#define NR (NN * RREL)                 // 250000 (dst,type) keys
#define NB5 ((NR + 255) / 256)         // 977

typedef __attribute__((ext_vector_type(8))) short short8;   // 8 bf16 (4 VGPRs)
typedef __attribute__((ext_vector_type(4))) float f32x4;
typedef unsigned short ushort_t;

static __device__ __forceinline__ float lrelu(float v) { return v > 0.f ? v : 0.01f * v; }

static __device__ __forceinline__ unsigned short f32_bf16_rn(float x) {
    unsigned u = __float_as_uint(x);
    return (unsigned short)((u + 0x7FFFu + ((u >> 16) & 1u)) >> 16);
}
static __device__ __forceinline__ float bf16_f32(unsigned short h) {
    return __uint_as_float(((unsigned)h) << 16);
}

// split 8 f32 (two float4) into bf16 hi + lo (x ~= hi + lo)
static __device__ __forceinline__ void split8v(float4 q0, float4 q1, short8& hi, short8& lo) {
    float v[8] = {q0.x, q0.y, q0.z, q0.w, q1.x, q1.y, q1.z, q1.w};
    #pragma unroll
    for (int j = 0; j < 8; ++j) {
        unsigned short h = f32_bf16_rn(v[j]);
        float hf = __uint_as_float(((unsigned)h) << 16);
        unsigned short l = f32_bf16_rn(v[j] - hf);
        hi[j] = (short)h; lo[j] = (short)l;
    }
}

static __device__ __forceinline__ short8 zero8() {
    short8 z = {0, 0, 0, 0, 0, 0, 0, 0};
    return z;
}

// ---------------------------------------------------------------------------
// zero_deg5: fast workspace zeroing (replaces hipMemsetAsync's slow fill)
// ---------------------------------------------------------------------------
__launch_bounds__(256)
__global__ void zero_deg5(int4* __restrict__ p, int n4)
{
    int i = blockIdx.x * 256 + threadIdx.x;
    int stride = gridDim.x * 256;
    for (; i < n4; i += stride)
        p[i] = make_int4(0, 0, 0, 0);
}

// ---------------------------------------------------------------------------
// lin_mfma: e0 = x @ field_W + field_b  (K=128), split-bf16 A (2 products),
// hi-only W frags pre-staged in 16 KB LDS. 512 thr, 128 rows/block.
// ---------------------------------------------------------------------------
__launch_bounds__(512)
__global__ void lin_mfma(const float* __restrict__ X,
                         const short8* __restrict__ ff,   // [16][64] hi frags
                         const float* __restrict__ bias,
                         float* __restrict__ C, ushort_t* __restrict__ Cb, int M)
{
    __shared__ short8 wl[16 * 64];   // 16 KB

    const int t = threadIdx.x;
    const int wid = t >> 6, lane = t & 63;
    const int lc = lane & 15, lg = lane >> 4;
    const int row0 = blockIdx.x * 128 + wid * 16;

    const int nA = row0 + lc;
    const bool okA = (nA < M);
    const int nodeA = okA ? nA : 0;

    wl[t] = ff[t];
    wl[t + 512] = ff[t + 512];

    short8 ah[4], al[4];
    #pragma unroll
    for (int s = 0; s < 4; ++s) {
        const float* p = &X[(size_t)nodeA * 128 + s * 32 + lg * 8];
        float4 q0 = okA ? *(const float4*)p       : make_float4(0,0,0,0);
        float4 q1 = okA ? *(const float4*)(p + 4) : make_float4(0,0,0,0);
        split8v(q0, q1, ah[s], al[s]);
    }
    __syncthreads();

    f32x4 acc[4];
    #pragma unroll
    for (int nf = 0; nf < 4; ++nf) acc[nf] = (f32x4){0.f, 0.f, 0.f, 0.f};

    #pragma unroll
    for (int s = 0; s < 4; ++s)
        #pragma unroll
        for (int nf = 0; nf < 4; ++nf) {
            short8 bh = wl[(s * 4 + nf) * 64 + lane];
            acc[nf] = __builtin_amdgcn_mfma_f32_16x16x32_bf16(ah[s], bh, acc[nf], 0, 0, 0);
            acc[nf] = __builtin_amdgcn_mfma_f32_16x16x32_bf16(al[s], bh, acc[nf], 0, 0, 0);
        }

    float bb[4];
    #pragma unroll
    for (int nf = 0; nf < 4; ++nf) bb[nf] = bias[nf * 16 + lc];

    #pragma unroll
    for (int i = 0; i < 4; ++i) {
        int nd = row0 + lg * 4 + i;
        if (nd >= M) continue;
        #pragma unroll
        for (int nf = 0; nf < 4; ++nf) {
            float v = acc[nf][i] + bb[nf];
            C[(size_t)nd * 64 + nf * 16 + lc] = v;
            Cb[(size_t)nd * 64 + nf * 16 + lc] = f32_bf16_rn(v);
        }
    }
}

// ---------------------------------------------------------------------------
// head_mfma: out = sum_src lrelu(E_src @ W_src + b_src).
// ---------------------------------------------------------------------------
__launch_bounds__(512)
__global__ void head_mfma(const float* __restrict__ E0, const float* __restrict__ E1,
                          const float* __restrict__ E2,
                          const short8* __restrict__ hf,   // [3][8][64] hi frags
                          const float* __restrict__ b0, const float* __restrict__ b1,
                          const float* __restrict__ b2,
                          float* __restrict__ out, int M)
{
    __shared__ short8 wl[24 * 64];   // 24 KB

    const int t = threadIdx.x;
    const int wid = t >> 6, lane = t & 63;
    const int lc = lane & 15, lg = lane >> 4;
    const int row0 = blockIdx.x * 128 + wid * 16;

    const int nA = row0 + lc;
    const bool okA = (nA < M);
    const int nodeA = okA ? nA : 0;

    wl[t] = hf[t];
    wl[t + 512] = hf[t + 512];
    wl[t + 1024] = hf[t + 1024];

    const float* Es[3] = {E0, E1, E2};
    const float* bs[3] = {b0, b1, b2};

    float facc[4][4] = {};   // [nf][i]
    __syncthreads();

    #pragma unroll
    for (int src = 0; src < 3; ++src) {
        short8 ah[2], al[2];
        #pragma unroll
        for (int s = 0; s < 2; ++s) {
            const float* p = &Es[src][(size_t)nodeA * 64 + s * 32 + lg * 8];
            float4 q0 = okA ? *(const float4*)p       : make_float4(0,0,0,0);
            float4 q1 = okA ? *(const float4*)(p + 4) : make_float4(0,0,0,0);
            split8v(q0, q1, ah[s], al[s]);
        }
        f32x4 acc[4];
        #pragma unroll
        for (int nf = 0; nf < 4; ++nf) acc[nf] = (f32x4){0.f, 0.f, 0.f, 0.f};
        #pragma unroll
        for (int s = 0; s < 2; ++s)
            #pragma unroll
            for (int nf = 0; nf < 4; ++nf) {
                short8 bh = wl[((src * 2 + s) * 4 + nf) * 64 + lane];
                acc[nf] = __builtin_amdgcn_mfma_f32_16x16x32_bf16(ah[s], bh, acc[nf], 0, 0, 0);
                acc[nf] = __builtin_amdgcn_mfma_f32_16x16x32_bf16(al[s], bh, acc[nf], 0, 0, 0);
            }
        float bb[4];
        #pragma unroll
        for (int nf = 0; nf < 4; ++nf) bb[nf] = bs[src][nf * 16 + lc];
        #pragma unroll
        for (int nf = 0; nf < 4; ++nf)
            #pragma unroll
            for (int i = 0; i < 4; ++i)
                facc[nf][i] += lrelu(acc[nf][i] + bb[nf]);
    }

    #pragma unroll
    for (int i = 0; i < 4; ++i) {
        int nd = row0 + lg * 4 + i;
        if (nd >= M) continue;
        #pragma unroll
        for (int nf = 0; nf < 4; ++nf)
            out[(size_t)nd * 64 + nf * 16 + lc] = facc[nf][i];
    }
}

// ---------------------------------------------------------------------------
// zgather v7: 8-deep pipelined walk; scalarized boundaries; bf16 in/out.
// ---------------------------------------------------------------------------
__launch_bounds__(256)
__global__ void zgather(const int* __restrict__ offs5,
                        const unsigned long long* __restrict__ epack,
                        const ushort_t* __restrict__ Eb,
                        ushort_t* __restrict__ Zb16, float* __restrict__ S)
{
    int wid = (blockIdx.x * 256 + threadIdx.x) >> 6;
    int lane = threadIdx.x & 63;
    if (wid >= NN) return;
    const int b = wid * RREL;

    int p    = __builtin_amdgcn_readfirstlane(offs5[b]);
    int n1   = __builtin_amdgcn_readfirstlane(offs5[b + 1]);
    int n2   = __builtin_amdgcn_readfirstlane(offs5[b + 2]);
    int n3   = __builtin_amdgcn_readfirstlane(offs5[b + 3]);
    int n4   = __builtin_amdgcn_readfirstlane(offs5[b + 4]);
    int pend = __builtin_amdgcn_readfirstlane(offs5[b + 5]);

    ushort_t* zr = Zb16 + (size_t)wid * 320 + lane;
    const int INFP = 0x7fffffff;

    int r = 0;
    float zA = 0.f, zB = 0.f, zC = 0.f, zD = 0.f;
    float sA = 0.f, sB = 0.f, sC = 0.f, sD = 0.f;

#define WVAL(q) __uint_as_float((unsigned)((q) >> 32))
#define SRCI(q) ((unsigned)(q) & 0xFFFFFFFFu)

#define FLUSH_CHECK(pe)                                                     \
    while (r < 4 && (pe) == n1) {                                           \
        zr[(size_t)(r << 6)] = f32_bf16_rn(zA + zB + zC + zD);              \
        if (lane == 0) S[b + r] = sA + sB + sC + sD;                        \
        zA = zB = zC = zD = 0.f; sA = sB = sC = sD = 0.f;                   \
        ++r; n1 = n2; n2 = n3; n3 = n4; n4 = INFP;                          \
    }

    for (; p + 8 <= pend; p += 8) {
        unsigned long long q0 = epack[p + 0];
        unsigned long long q1 = epack[p + 1];
        unsigned long long q2 = epack[p + 2];
        unsigned long long q3 = epack[p + 3];
        unsigned long long q4 = epack[p + 4];
        unsigned long long q5 = epack[p + 5];
        unsigned long long q6 = epack[p + 6];
        unsigned long long q7 = epack[p + 7];
        float v0 = bf16_f32(Eb[(size_t)SRCI(q0) * 64 + lane]);
        float v1 = bf16_f32(Eb[(size_t)SRCI(q1) * 64 + lane]);
        float v2 = bf16_f32(Eb[(size_t)SRCI(q2) * 64 + lane]);
        float v3 = bf16_f32(Eb[(size_t)SRCI(q3) * 64 + lane]);
        float v4 = bf16_f32(Eb[(size_t)SRCI(q4) * 64 + lane]);
        float v5 = bf16_f32(Eb[(size_t)SRCI(q5) * 64 + lane]);
        float v6 = bf16_f32(Eb[(size_t)SRCI(q6) * 64 + lane]);
        float v7 = bf16_f32(Eb[(size_t)SRCI(q7) * 64 + lane]);

        FLUSH_CHECK(p + 0);
        zA = fmaf(WVAL(q0), v0, zA); sA += WVAL(q0);
        FLUSH_CHECK(p + 1);
        zB = fmaf(WVAL(q1), v1, zB); sB += WVAL(q1);
        FLUSH_CHECK(p + 2);
        zC = fmaf(WVAL(q2), v2, zC); sC += WVAL(q2);
        FLUSH_CHECK(p + 3);
        zD = fmaf(WVAL(q3), v3, zD); sD += WVAL(q3);
        FLUSH_CHECK(p + 4);
        zA = fmaf(WVAL(q4), v4, zA); sA += WVAL(q4);
        FLUSH_CHECK(p + 5);
        zB = fmaf(WVAL(q5), v5, zB); sB += WVAL(q5);
        FLUSH_CHECK(p + 6);
        zC = fmaf(WVAL(q6), v6, zC); sC += WVAL(q6);
        FLUSH_CHECK(p + 7);
        zD = fmaf(WVAL(q7), v7, zD); sD += WVAL(q7);
    }
    for (; p < pend; ++p) {
        unsigned long long q = epack[p];
        float v = bf16_f32(Eb[(size_t)SRCI(q) * 64 + lane]);
        FLUSH_CHECK(p);
        zA = fmaf(WVAL(q), v, zA);
        sA += WVAL(q);
    }
    while (r < RREL) {
        zr[(size_t)(r << 6)] = f32_bf16_rn(zA + zB + zC + zD);
        if (lane == 0) S[b + r] = sA + sB + sC + sD;
        zA = zB = zC = zD = 0.f; sA = sB = sC = sD = 0.f;
        ++r;
    }
#undef FLUSH_CHECK
#undef WVAL
#undef SRCI
}

// ---------------------------------------------------------------------------
// prep_wfrag: weight fragment prep (rel hi+lo; field hi; head hi).
// ---------------------------------------------------------------------------
__launch_bounds__(256)
__global__ void prep_wfrag(const float* __restrict__ rel1_W, const float* __restrict__ rel2_W,
                           const float* __restrict__ field_W,
                           const float* __restrict__ out0_W, const float* __restrict__ out1_W,
                           const float* __restrict__ out2_W,
                           short8* __restrict__ wf1, short8* __restrict__ wf2,
                           short8* __restrict__ ff, short8* __restrict__ hf)
{
    int bid = blockIdx.x;
    int t = threadIdx.x;

    if (bid < 20) {
        int layer = bid / 10, c = bid % 10;
        const float* relW = layer ? rel2_W : rel1_W;
        short8* wf = layer ? wf2 : wf1;
        for (int sl = t; sl < 512; sl += 256) {
            int rid = sl >> 6, lane = sl & 63;
            int s = rid >> 2, nf = rid & 3;
            int g = lane >> 4, lc = lane & 15;
            int r = (c < 5) ? c : c - 5;
            const float* W = relW + (size_t)r * 8192 + ((c < 5) ? 0 : 4096);
            float v[8];
            #pragma unroll
            for (int j = 0; j < 8; ++j)
                v[j] = W[(size_t)(s * 32 + g * 8 + j) * 64 + nf * 16 + lc];
            float4 q0 = make_float4(v[0], v[1], v[2], v[3]);
            float4 q1 = make_float4(v[4], v[5], v[6], v[7]);
            short8 hi, lo;
            split8v(q0, q1, hi, lo);
            size_t slot = (size_t)c * 1024 + (size_t)((s * 4 + nf) * 64 + lane) * 2;
            wf[slot]     = hi;
            wf[slot + 1] = lo;
        }
    } else if (bid < 24) {
        int s = bid - 20;             // K-slice 0..3
        for (int sl = t; sl < 256; sl += 256) {
            int nf = sl >> 6, lane = sl & 63;
            int g = lane >> 4, lc = lane & 15;
            float v[8];
            #pragma unroll
            for (int j = 0; j < 8; ++j)
                v[j] = field_W[(size_t)(s * 32 + g * 8 + j) * 64 + nf * 16 + lc];
            short8 hi;
            #pragma unroll
            for (int j = 0; j < 8; ++j) hi[j] = (short)f32_bf16_rn(v[j]);
            ff[(size_t)(s * 4 + nf) * 64 + lane] = hi;
        }
    } else {
        int hsrc = bid - 24;          // 0..2
        const float* W = (hsrc == 0) ? out0_W : (hsrc == 1) ? out1_W : out2_W;
        for (int sl = t; sl < 512; sl += 256) {
            int rid = sl >> 6, lane = sl & 63;
            int s = rid >> 2, nf = rid & 3;
            if (s >= 2) continue;
            int g = lane >> 4, lc = lane & 15;
            float v[8];
            #pragma unroll
            for (int j = 0; j < 8; ++j)
                v[j] = W[(size_t)(s * 32 + g * 8 + j) * 64 + nf * 16 + lc];
            short8 hi;
            #pragma unroll
            for (int j = 0; j < 8; ++j) hi[j] = (short)f32_bf16_rn(v[j]);
            hf[(size_t)((hsrc * 2 + s) * 4 + nf) * 64 + lane] = hi;
        }
    }
}

// ---------------------------------------------------------------------------
// zgemm_mfma v3: 2-phase LDS pipeline; Z bf16 direct fragments.
// ---------------------------------------------------------------------------
__launch_bounds__(512)
__global__ void zgemm_mfma(const ushort_t* __restrict__ Zb16,
                           const float* __restrict__ Eprev,
                           const short8* __restrict__ wf,
                           const float* __restrict__ relb,
                           const float* __restrict__ S,
                           float* __restrict__ Enext, ushort_t* __restrict__ Enb, int M)
{
    __shared__ short8 wlds[2][1024];   // 2 x 16 KB

    const int t = threadIdx.x;
    const int wid = t >> 6, lane = t & 63;
    const int lc = lane & 15, lg = lane >> 4;
    const int row0 = blockIdx.x * 128 + wid * 16;

    const int nA = row0 + lc;
    const bool okA = (nA < M);
    const int nodeA = okA ? nA : 0;

    const int sq = t >> 6, sl = t & 63;
    const int wrA = (sq * 2 + 0) * 64 + sl;
    const int wrB = (sq * 2 + 1) * 64 + sl;

    short8 eh[2], el[2];
    #pragma unroll
    for (int s = 0; s < 2; ++s) {
        const float* p = &Eprev[(size_t)nodeA * 64 + s * 32 + lg * 8];
        float4 q0 = okA ? *(const float4*)p       : make_float4(0,0,0,0);
        float4 q1 = okA ? *(const float4*)(p + 4) : make_float4(0,0,0,0);
        split8v(q0, q1, eh[s], el[s]);
    }

    float sD[4][RREL];
    #pragma unroll
    for (int i = 0; i < 4; ++i) {
        int nd = row0 + lg * 4 + i;
        int ns = (nd < M) ? nd : 0;
        #pragma unroll
        for (int r = 0; r < RREL; ++r)
            sD[i][r] = S[(size_t)ns * RREL + r];
    }

    {
        const short8* wp = wf + (size_t)t * 2;
        short8 sa = wp[0], sb = wp[1];
        wlds[0][wrA] = sa; wlds[0][wrB] = sb;
    }
    short8 az0, az1;
    {
        const ushort_t* zb = &Zb16[(size_t)nodeA * 320 + lg * 8];
        az0 = okA ? *(const short8*)(zb)      : zero8();
        az1 = okA ? *(const short8*)(zb + 32) : zero8();
    }
    __syncthreads();

    f32x4 acc[4];
    #pragma unroll
    for (int nf = 0; nf < 4; ++nf) acc[nf] = (f32x4){0.f, 0.f, 0.f, 0.f};

    short8 sreg_a, sreg_b;
    short8 pz0, pz1;

    #pragma unroll
    for (int c = 0; c < 10; ++c) {
        const int cb = c & 1;
        if (c < 9) {
            const short8* wp = wf + (size_t)(c + 1) * 1024 + (size_t)t * 2;
            sreg_a = wp[0]; sreg_b = wp[1];
        }
        if (c < 4) {
            const ushort_t* zb = &Zb16[(size_t)nodeA * 320 + (c + 1) * 64 + lg * 8];
            pz0 = okA ? *(const short8*)(zb)      : zero8();
            pz1 = okA ? *(const short8*)(zb + 32) : zero8();
        }

        if (c < 5) {
            #pragma unroll
            for (int s = 0; s < 2; ++s) {
                short8 Az = (s == 0) ? az0 : az1;
                #pragma unroll
                for (int nf = 0; nf < 4; ++nf) {
                    short8 bh = wlds[cb][((s * 4 + nf) * 2 + 0) * 64 + lane];
                    short8 bl = wlds[cb][((s * 4 + nf) * 2 + 1) * 64 + lane];
                    acc[nf] = __builtin_amdgcn_mfma_f32_16x16x32_bf16(Az, bh, acc[nf], 0, 0, 0);
                    acc[nf] = __builtin_amdgcn_mfma_f32_16x16x32_bf16(Az, bl, acc[nf], 0, 0, 0);
                }
            }
        } else {
            f32x4 tmp[4];
            #pragma unroll
            for (int nf = 0; nf < 4; ++nf) tmp[nf] = (f32x4){0.f, 0.f, 0.f, 0.f};
            #pragma unroll
            for (int s = 0; s < 2; ++s)
                #pragma unroll
                for (int nf = 0; nf < 4; ++nf) {
                    short8 bh = wlds[cb][((s * 4 + nf) * 2 + 0) * 64 + lane];
                    short8 bl = wlds[cb][((s * 4 + nf) * 2 + 1) * 64 + lane];
                    tmp[nf] = __builtin_amdgcn_mfma_f32_16x16x32_bf16(eh[s], bh, tmp[nf], 0, 0, 0);
                    tmp[nf] = __builtin_amdgcn_mfma_f32_16x16x32_bf16(el[s], bh, tmp[nf], 0, 0, 0);
                    tmp[nf] = __builtin_amdgcn_mfma_f32_16x16x32_bf16(eh[s], bl, tmp[nf], 0, 0, 0);
                }
            const int r = c - 5;
            #pragma unroll
            for (int nf = 0; nf < 4; ++nf)
                #pragma unroll
                for (int i = 0; i < 4; ++i)
                    acc[nf][i] += sD[i][r] * tmp[nf][i];
        }

        if (c < 4) { az0 = pz0; az1 = pz1; }

        if (c < 9) {
            __syncthreads();
            wlds[cb ^ 1][wrA] = sreg_a;
            wlds[cb ^ 1][wrB] = sreg_b;
            __syncthreads();
        }
    }

    float bbv[4][RREL];
    #pragma unroll
    for (int nf = 0; nf < 4; ++nf)
        #pragma unroll
        for (int r = 0; r < RREL; ++r)
            bbv[nf][r] = relb[r * 64 + nf * 16 + lc];

    #pragma unroll
    for (int i = 0; i < 4; ++i) {
        int nd = row0 + lg * 4 + i;
        if (nd >= M) continue;
        #pragma unroll
        for (int nf = 0; nf < 4; ++nf) {
            float v = acc[nf][i];
            #pragma unroll
            for (int r = 0; r < RREL; ++r)
                v += sD[i][r] * bbv[nf][r];
            Enext[(size_t)nd * 64 + nf * 16 + lc] = v;
            if (Enb) Enb[(size_t)nd * 64 + nf * 16 + lc] = f32_bf16_rn(v);
        }
    }
}

// ---------------------------------------------------------------------------
// CSR build over (dst,type) keys
// ---------------------------------------------------------------------------
__launch_bounds__(256)
__global__ void deg5_hist(const int* __restrict__ dst, const int* __restrict__ etype,
                          int* __restrict__ deg5, int* __restrict__ slot5)
{
    int e = blockIdx.x * 256 + threadIdx.x;
    if (e < NE) slot5[e] = atomicAdd(&deg5[dst[e] * RREL + etype[e]], 1);
}

__launch_bounds__(256)
__global__ void b1_reduce(const int* __restrict__ deg5, int* __restrict__ b1)
{
    __shared__ int sh[256];
    int i = blockIdx.x * 256 + threadIdx.x;
    sh[threadIdx.x] = (i < NR) ? deg5[i] : 0;
    __syncthreads();
    for (int s = 128; s > 0; s >>= 1) {
        if (threadIdx.x < s) sh[threadIdx.x] += sh[threadIdx.x + s];
        __syncthreads();
    }
    if (threadIdx.x == 0) b1[blockIdx.x] = sh[0];
}

__launch_bounds__(256)
__global__ void scan_seq(int* __restrict__ b1, int n)
{
    __shared__ int sh[256];
    __shared__ int carry;
    if (threadIdx.x == 0) carry = 0;
    __syncthreads();
    for (int base = 0; base < n; base += 256) {
        int i = base + threadIdx.x;
        int v = (i < n) ? b1[i] : 0;
        sh[threadIdx.x] = v;
        __syncthreads();
        for (int off = 1; off < 256; off <<= 1) {
            int x = (threadIdx.x >= off) ? sh[threadIdx.x - off] : 0;
            __syncthreads();
            sh[threadIdx.x] += x;
            __syncthreads();
        }
        int excl = sh[threadIdx.x] - v + carry;
        if (i < n) b1[i] = excl;
        __syncthreads();
        if (threadIdx.x == 255) carry = excl + v;
        __syncthreads();
    }
}

__launch_bounds__(256)
__global__ void offs5_final(const int* __restrict__ deg5, const int* __restrict__ b1,
                            int* __restrict__ offs5)
{
    __shared__ int sh[256];
    int t = threadIdx.x;
    int i = blockIdx.x * 256 + t;
    int v = (i < NR) ? deg5[i] : 0;
    sh[t] = v;
    __syncthreads();
    for (int off = 1; off < 256; off <<= 1) {
        int x = (t >= off) ? sh[t - off] : 0;
        __syncthreads();
        sh[t] += x;
        __syncthreads();
    }
    int excl = sh[t] - v + b1[blockIdx.x];
    if (i <= NR) offs5[i] = excl;
}

// scatter: epack[offs5[dst*5+r] + slot5[e]] = {w, src} packed u64
__launch_bounds__(256)
__global__ void scatter_pass(const int* __restrict__ src, const int* __restrict__ dst,
                             const int* __restrict__ etype,
                             const float* __restrict__ etime,
                             const float* __restrict__ beta,
                             const float* __restrict__ lambda_p,
                             const int* __restrict__ slot5, const int* __restrict__ offs5,
                             unsigned long long* __restrict__ epack)
{
    int e = blockIdx.x * 256 + threadIdx.x;
    if (e >= NE) return;
    float b[12];
    #pragma unroll
    for (int j = 0; j < 12; ++j) b[j] = beta[j];
    const float* et = etime + (size_t)e * 12;
    float4 v0 = *(const float4*)(et);
    float4 v1 = *(const float4*)(et + 4);
    float4 v2 = *(const float4*)(et + 8);
    float logit = v0.x*b[0] + v0.y*b[1] + v0.z*b[2] + v0.w*b[3]
                + v1.x*b[4] + v1.y*b[5] + v1.z*b[6] + v1.w*b[7]
                + v2.x*b[8] + v2.y*b[9] + v2.z*b[10] + v2.w*b[11];
    float we = lambda_p[0] * expf(-logit);
    int p = offs5[dst[e] * RREL + etype[e]] + slot5[e];
    epack[p] = ((unsigned long long)__float_as_uint(we) << 32) | (unsigned)src[e];
}

// ---------------------------------------------------------------------------
extern "C" void kernel_launch(void* const* d_in, const int* in_sizes, int n_in,
                              void* d_out, int out_size, void* d_ws, size_t ws_size,
                              hipStream_t stream)
{
    const float* x        = (const float*)d_in[0];
    const int*   eidx     = (const int*)d_in[1];
    const int*   etype    = (const int*)d_in[2];
    const float* etime    = (const float*)d_in[3];
    const float* lambda_p = (const float*)d_in[4];
    const float* beta     = (const float*)d_in[5];
    const float* field_W  = (const float*)d_in[6];
    const float* field_b  = (const float*)d_in[7];
    const float* rel1_W   = (const float*)d_in[8];
    const float* rel1_b   = (const float*)d_in[9];
    const float* rel2_W   = (const float*)d_in[10];
    const float* rel2_b   = (const float*)d_in[11];
    const float* out0_W   = (const float*)d_in[12];
    const float* out0_b   = (const float*)d_in[13];
    const float* out1_W   = (const float*)d_in[14];
    const float* out1_b   = (const float*)d_in[15];
    const float* out2_W   = (const float*)d_in[16];
    const float* out2_b   = (const float*)d_in[17];
    const int* src = eidx;
    const int* dst = eidx + NE;
    float* out = (float*)d_out;

    char* wsb = (char*)d_ws;
    size_t off = 0;
    auto carve = [&](size_t bytes) -> void* {
        void* p = (void*)(wsb + off);
        off += (bytes + 255) & ~(size_t)255;
        return p;
    };
    int*   deg5   = (int*)carve((size_t)NR * 4);            // 1 MB
    int*   offs5  = (int*)carve((size_t)(NR + 1) * 4);      // 1 MB
    int*   b1     = (int*)carve((size_t)NB5 * 4);
    int*   slot5  = (int*)carve((size_t)NE * 4);            // 3.2 MB
    float* S      = (float*)carve((size_t)NR * 4);          // 1 MB
    unsigned long long* epack = (unsigned long long*)carve((size_t)NE * 8); // 6.4 MB
    float* e0     = (float*)carve((size_t)NN * 64 * 4);     // 12.8 MB
    float* e1     = (float*)carve((size_t)NN * 64 * 4);     // 12.8 MB
    float* e2     = (float*)carve((size_t)NN * 64 * 4);     // 12.8 MB
    ushort_t* e0b = (ushort_t*)carve((size_t)NN * 64 * 2);  // 6.4 MB bf16 shadow
    ushort_t* e1b = (ushort_t*)carve((size_t)NN * 64 * 2);  // 6.4 MB bf16 shadow
    ushort_t* Zb16 = (ushort_t*)carve((size_t)NN * 320 * 2); // 32 MB bf16 Z
    short8* wf1   = (short8*)carve((size_t)20 * 16384);     // 320 KB
    short8* wf2   = (short8*)carve((size_t)20 * 16384);     // 320 KB
    short8* ff    = (short8*)carve((size_t)16 * 64 * 16);   // 16 KB field frags
    short8* hf    = (short8*)carve((size_t)24 * 64 * 16);   // 24 KB head frags

    dim3 blk(256);
    const int NT128 = (NN + 127) / 128;     // 391
    const int EB = (NE + 255) / 256;
    const int GB = (NN * 64 + 255) / 256;   // one wave per node

    // ---- CSR build over (dst,type) + weight frag prep ----
    zero_deg5<<<256, blk, 0, stream>>>((int4*)deg5, (NR + 3) / 4);
    deg5_hist<<<EB, blk, 0, stream>>>(dst, etype, deg5, slot5);
    prep_wfrag<<<27, blk, 0, stream>>>(rel1_W, rel2_W, field_W, out0_W, out1_W, out2_W,
                                       wf1, wf2, ff, hf);
    b1_reduce<<<NB5, blk, 0, stream>>>(deg5, b1);
    scan_seq<<<1, blk, 0, stream>>>(b1, NB5);
    offs5_final<<<NB5, blk, 0, stream>>>(deg5, b1, offs5);
    scatter_pass<<<EB, blk, 0, stream>>>(src, dst, etype, etime, beta, lambda_p,
                                         slot5, offs5, epack);

    // ---- e0 = x @ field_W + field_b (MFMA, + bf16 shadow) ----
    lin_mfma<<<dim3(NT128), dim3(512), 0, stream>>>(x, ff, field_b, e0, e0b, NN);

    // ---- layer 1 ----
    zgather<<<GB, blk, 0, stream>>>(offs5, epack, e0b, Zb16, S);
    zgemm_mfma<<<dim3(NT128), dim3(512), 0, stream>>>(Zb16, e0, wf1, rel1_b, S, e1, e1b, NN);

    // ---- layer 2 ----
    zgather<<<GB, blk, 0, stream>>>(offs5, epack, e1b, Zb16, S);
    zgemm_mfma<<<dim3(NT128), dim3(512), 0, stream>>>(Zb16, e1, wf2, rel2_b, S, e2, nullptr, NN);

    // ---- output head (MFMA, single pass) ----
    head_mfma<<<dim3(NT128), dim3(512), 0, stream>>>(e0, e1, e2, hf,
                                                     out0_b, out1_b, out2_b, out, NN);
}

// Round 17
// 204.034 us; speedup vs baseline: 1.5436x; 1.0562x over previous
//
#include <hip/hip_runtime.h>
#include <cstdint>
#include <cstddef>

#define NN 50000
#define NE 800000
#define RREL 5
#define NR (NN * RREL)                 // 250000 (dst,type) keys
#define NB5 ((NR + 255) / 256)         // 977

typedef __attribute__((ext_vector_type(8))) short short8;   // 8 bf16 (4 VGPRs)
typedef __attribute__((ext_vector_type(4))) float f32x4;
typedef unsigned short ushort_t;

static __device__ __forceinline__ float lrelu(float v) { return v > 0.f ? v : 0.01f * v; }

static __device__ __forceinline__ unsigned short f32_bf16_rn(float x) {
    unsigned u = __float_as_uint(x);
    return (unsigned short)((u + 0x7FFFu + ((u >> 16) & 1u)) >> 16);
}
static __device__ __forceinline__ float bf16_f32(unsigned short h) {
    return __uint_as_float(((unsigned)h) << 16);
}

// split 8 f32 (two float4) into bf16 hi + lo (x ~= hi + lo)
static __device__ __forceinline__ void split8v(float4 q0, float4 q1, short8& hi, short8& lo) {
    float v[8] = {q0.x, q0.y, q0.z, q0.w, q1.x, q1.y, q1.z, q1.w};
    #pragma unroll
    for (int j = 0; j < 8; ++j) {
        unsigned short h = f32_bf16_rn(v[j]);
        float hf = __uint_as_float(((unsigned)h) << 16);
        unsigned short l = f32_bf16_rn(v[j] - hf);
        hi[j] = (short)h; lo[j] = (short)l;
    }
}

static __device__ __forceinline__ short8 zero8() {
    short8 z = {0, 0, 0, 0, 0, 0, 0, 0};
    return z;
}

// ---------------------------------------------------------------------------
// zero_deg5: fast workspace zeroing
// ---------------------------------------------------------------------------
__launch_bounds__(256)
__global__ void zero_deg5(int4* __restrict__ p, int n4)
{
    int i = blockIdx.x * 256 + threadIdx.x;
    int stride = gridDim.x * 256;
    for (; i < n4; i += stride)
        p[i] = make_int4(0, 0, 0, 0);
}

// ---------------------------------------------------------------------------
// lin_mfma: e0b = bf16(x @ field_W + field_b)  (K=128), split-bf16 A,
// hi-only W frags in 16 KB LDS. 512 thr, 128 rows/block.
// ---------------------------------------------------------------------------
__launch_bounds__(512)
__global__ void lin_mfma(const float* __restrict__ X,
                         const short8* __restrict__ ff,   // [16][64] hi frags
                         const float* __restrict__ bias,
                         ushort_t* __restrict__ Cb, int M)
{
    __shared__ short8 wl[16 * 64];   // 16 KB

    const int t = threadIdx.x;
    const int wid = t >> 6, lane = t & 63;
    const int lc = lane & 15, lg = lane >> 4;
    const int row0 = blockIdx.x * 128 + wid * 16;

    const int nA = row0 + lc;
    const bool okA = (nA < M);
    const int nodeA = okA ? nA : 0;

    wl[t] = ff[t];
    wl[t + 512] = ff[t + 512];

    short8 ah[4], al[4];
    #pragma unroll
    for (int s = 0; s < 4; ++s) {
        const float* p = &X[(size_t)nodeA * 128 + s * 32 + lg * 8];
        float4 q0 = okA ? *(const float4*)p       : make_float4(0,0,0,0);
        float4 q1 = okA ? *(const float4*)(p + 4) : make_float4(0,0,0,0);
        split8v(q0, q1, ah[s], al[s]);
    }
    __syncthreads();

    f32x4 acc[4];
    #pragma unroll
    for (int nf = 0; nf < 4; ++nf) acc[nf] = (f32x4){0.f, 0.f, 0.f, 0.f};

    #pragma unroll
    for (int s = 0; s < 4; ++s)
        #pragma unroll
        for (int nf = 0; nf < 4; ++nf) {
            short8 bh = wl[(s * 4 + nf) * 64 + lane];
            acc[nf] = __builtin_amdgcn_mfma_f32_16x16x32_bf16(ah[s], bh, acc[nf], 0, 0, 0);
            acc[nf] = __builtin_amdgcn_mfma_f32_16x16x32_bf16(al[s], bh, acc[nf], 0, 0, 0);
        }

    float bb[4];
    #pragma unroll
    for (int nf = 0; nf < 4; ++nf) bb[nf] = bias[nf * 16 + lc];

    #pragma unroll
    for (int i = 0; i < 4; ++i) {
        int nd = row0 + lg * 4 + i;
        if (nd >= M) continue;
        #pragma unroll
        for (int nf = 0; nf < 4; ++nf)
            Cb[(size_t)nd * 64 + nf * 16 + lc] = f32_bf16_rn(acc[nf][i] + bb[nf]);
    }
}

// ---------------------------------------------------------------------------
// head_mfma: out = sum_src lrelu(Eb_src @ W_src + b_src). A = bf16 frags
// loaded directly; W hi-only (24 KB LDS).
// ---------------------------------------------------------------------------
__launch_bounds__(512)
__global__ void head_mfma(const ushort_t* __restrict__ E0, const ushort_t* __restrict__ E1,
                          const ushort_t* __restrict__ E2,
                          const short8* __restrict__ hf,   // [3][8][64] hi frags
                          const float* __restrict__ b0, const float* __restrict__ b1,
                          const float* __restrict__ b2,
                          float* __restrict__ out, int M)
{
    __shared__ short8 wl[24 * 64];   // 24 KB

    const int t = threadIdx.x;
    const int wid = t >> 6, lane = t & 63;
    const int lc = lane & 15, lg = lane >> 4;
    const int row0 = blockIdx.x * 128 + wid * 16;

    const int nA = row0 + lc;
    const bool okA = (nA < M);
    const int nodeA = okA ? nA : 0;

    wl[t] = hf[t];
    wl[t + 512] = hf[t + 512];
    wl[t + 1024] = hf[t + 1024];

    const ushort_t* Es[3] = {E0, E1, E2};
    const float* bs[3] = {b0, b1, b2};

    float facc[4][4] = {};   // [nf][i]
    __syncthreads();

    #pragma unroll
    for (int src = 0; src < 3; ++src) {
        short8 ah[2];
        #pragma unroll
        for (int s = 0; s < 2; ++s) {
            const ushort_t* p = &Es[src][(size_t)nodeA * 64 + s * 32 + lg * 8];
            ah[s] = okA ? *(const short8*)p : zero8();
        }
        f32x4 acc[4];
        #pragma unroll
        for (int nf = 0; nf < 4; ++nf) acc[nf] = (f32x4){0.f, 0.f, 0.f, 0.f};
        #pragma unroll
        for (int s = 0; s < 2; ++s)
            #pragma unroll
            for (int nf = 0; nf < 4; ++nf) {
                short8 bh = wl[((src * 2 + s) * 4 + nf) * 64 + lane];
                acc[nf] = __builtin_amdgcn_mfma_f32_16x16x32_bf16(ah[s], bh, acc[nf], 0, 0, 0);
            }
        float bb[4];
        #pragma unroll
        for (int nf = 0; nf < 4; ++nf) bb[nf] = bs[src][nf * 16 + lc];
        #pragma unroll
        for (int nf = 0; nf < 4; ++nf)
            #pragma unroll
            for (int i = 0; i < 4; ++i)
                facc[nf][i] += lrelu(acc[nf][i] + bb[nf]);
    }

    #pragma unroll
    for (int i = 0; i < 4; ++i) {
        int nd = row0 + lg * 4 + i;
        if (nd >= M) continue;
        #pragma unroll
        for (int nf = 0; nf < 4; ++nf)
            out[(size_t)nd * 64 + nf * 16 + lc] = facc[nf][i];
    }
}

// ---------------------------------------------------------------------------
// zgather v7: 8-deep pipelined walk; scalarized boundaries; bf16 in/out.
// ---------------------------------------------------------------------------
__launch_bounds__(256)
__global__ void zgather(const int* __restrict__ offs5,
                        const unsigned long long* __restrict__ epack,
                        const ushort_t* __restrict__ Eb,
                        ushort_t* __restrict__ Zb16, float* __restrict__ S)
{
    int wid = (blockIdx.x * 256 + threadIdx.x) >> 6;
    int lane = threadIdx.x & 63;
    if (wid >= NN) return;
    const int b = wid * RREL;

    int p    = __builtin_amdgcn_readfirstlane(offs5[b]);
    int n1   = __builtin_amdgcn_readfirstlane(offs5[b + 1]);
    int n2   = __builtin_amdgcn_readfirstlane(offs5[b + 2]);
    int n3   = __builtin_amdgcn_readfirstlane(offs5[b + 3]);
    int n4   = __builtin_amdgcn_readfirstlane(offs5[b + 4]);
    int pend = __builtin_amdgcn_readfirstlane(offs5[b + 5]);

    ushort_t* zr = Zb16 + (size_t)wid * 320 + lane;
    const int INFP = 0x7fffffff;

    int r = 0;
    float zA = 0.f, zB = 0.f, zC = 0.f, zD = 0.f;
    float sA = 0.f, sB = 0.f, sC = 0.f, sD = 0.f;

#define WVAL(q) __uint_as_float((unsigned)((q) >> 32))
#define SRCI(q) ((unsigned)(q) & 0xFFFFFFFFu)

#define FLUSH_CHECK(pe)                                                     \
    while (r < 4 && (pe) == n1) {                                           \
        zr[(size_t)(r << 6)] = f32_bf16_rn(zA + zB + zC + zD);              \
        if (lane == 0) S[b + r] = sA + sB + sC + sD;                        \
        zA = zB = zC = zD = 0.f; sA = sB = sC = sD = 0.f;                   \
        ++r; n1 = n2; n2 = n3; n3 = n4; n4 = INFP;                          \
    }

    for (; p + 8 <= pend; p += 8) {
        unsigned long long q0 = epack[p + 0];
        unsigned long long q1 = epack[p + 1];
        unsigned long long q2 = epack[p + 2];
        unsigned long long q3 = epack[p + 3];
        unsigned long long q4 = epack[p + 4];
        unsigned long long q5 = epack[p + 5];
        unsigned long long q6 = epack[p + 6];
        unsigned long long q7 = epack[p + 7];
        float v0 = bf16_f32(Eb[(size_t)SRCI(q0) * 64 + lane]);
        float v1 = bf16_f32(Eb[(size_t)SRCI(q1) * 64 + lane]);
        float v2 = bf16_f32(Eb[(size_t)SRCI(q2) * 64 + lane]);
        float v3 = bf16_f32(Eb[(size_t)SRCI(q3) * 64 + lane]);
        float v4 = bf16_f32(Eb[(size_t)SRCI(q4) * 64 + lane]);
        float v5 = bf16_f32(Eb[(size_t)SRCI(q5) * 64 + lane]);
        float v6 = bf16_f32(Eb[(size_t)SRCI(q6) * 64 + lane]);
        float v7 = bf16_f32(Eb[(size_t)SRCI(q7) * 64 + lane]);

        FLUSH_CHECK(p + 0);
        zA = fmaf(WVAL(q0), v0, zA); sA += WVAL(q0);
        FLUSH_CHECK(p + 1);
        zB = fmaf(WVAL(q1), v1, zB); sB += WVAL(q1);
        FLUSH_CHECK(p + 2);
        zC = fmaf(WVAL(q2), v2, zC); sC += WVAL(q2);
        FLUSH_CHECK(p + 3);
        zD = fmaf(WVAL(q3), v3, zD); sD += WVAL(q3);
        FLUSH_CHECK(p + 4);
        zA = fmaf(WVAL(q4), v4, zA); sA += WVAL(q4);
        FLUSH_CHECK(p + 5);
        zB = fmaf(WVAL(q5), v5, zB); sB += WVAL(q5);
        FLUSH_CHECK(p + 6);
        zC = fmaf(WVAL(q6), v6, zC); sC += WVAL(q6);
        FLUSH_CHECK(p + 7);
        zD = fmaf(WVAL(q7), v7, zD); sD += WVAL(q7);
    }
    for (; p < pend; ++p) {
        unsigned long long q = epack[p];
        float v = bf16_f32(Eb[(size_t)SRCI(q) * 64 + lane]);
        FLUSH_CHECK(p);
        zA = fmaf(WVAL(q), v, zA);
        sA += WVAL(q);
    }
    while (r < RREL) {
        zr[(size_t)(r << 6)] = f32_bf16_rn(zA + zB + zC + zD);
        if (lane == 0) S[b + r] = sA + sB + sC + sD;
        zA = zB = zC = zD = 0.f; sA = sB = sC = sD = 0.f;
        ++r;
    }
#undef FLUSH_CHECK
#undef WVAL
#undef SRCI
}

// ---------------------------------------------------------------------------
// prep_wfrag: weight fragment prep (rel hi+lo; field hi; head hi).
// ---------------------------------------------------------------------------
__launch_bounds__(256)
__global__ void prep_wfrag(const float* __restrict__ rel1_W, const float* __restrict__ rel2_W,
                           const float* __restrict__ field_W,
                           const float* __restrict__ out0_W, const float* __restrict__ out1_W,
                           const float* __restrict__ out2_W,
                           short8* __restrict__ wf1, short8* __restrict__ wf2,
                           short8* __restrict__ ff, short8* __restrict__ hf)
{
    int bid = blockIdx.x;
    int t = threadIdx.x;

    if (bid < 20) {
        int layer = bid / 10, c = bid % 10;
        const float* relW = layer ? rel2_W : rel1_W;
        short8* wf = layer ? wf2 : wf1;
        for (int sl = t; sl < 512; sl += 256) {
            int rid = sl >> 6, lane = sl & 63;
            int s = rid >> 2, nf = rid & 3;
            int g = lane >> 4, lc = lane & 15;
            int r = (c < 5) ? c : c - 5;
            const float* W = relW + (size_t)r * 8192 + ((c < 5) ? 0 : 4096);
            float v[8];
            #pragma unroll
            for (int j = 0; j < 8; ++j)
                v[j] = W[(size_t)(s * 32 + g * 8 + j) * 64 + nf * 16 + lc];
            float4 q0 = make_float4(v[0], v[1], v[2], v[3]);
            float4 q1 = make_float4(v[4], v[5], v[6], v[7]);
            short8 hi, lo;
            split8v(q0, q1, hi, lo);
            size_t slot = (size_t)c * 1024 + (size_t)((s * 4 + nf) * 64 + lane) * 2;
            wf[slot]     = hi;
            wf[slot + 1] = lo;
        }
    } else if (bid < 24) {
        int s = bid - 20;             // K-slice 0..3
        for (int sl = t; sl < 256; sl += 256) {
            int nf = sl >> 6, lane = sl & 63;
            int g = lane >> 4, lc = lane & 15;
            float v[8];
            #pragma unroll
            for (int j = 0; j < 8; ++j)
                v[j] = field_W[(size_t)(s * 32 + g * 8 + j) * 64 + nf * 16 + lc];
            short8 hi;
            #pragma unroll
            for (int j = 0; j < 8; ++j) hi[j] = (short)f32_bf16_rn(v[j]);
            ff[(size_t)(s * 4 + nf) * 64 + lane] = hi;
        }
    } else {
        int hsrc = bid - 24;          // 0..2
        const float* W = (hsrc == 0) ? out0_W : (hsrc == 1) ? out1_W : out2_W;
        for (int sl = t; sl < 512; sl += 256) {
            int rid = sl >> 6, lane = sl & 63;
            int s = rid >> 2, nf = rid & 3;
            if (s >= 2) continue;
            int g = lane >> 4, lc = lane & 15;
            float v[8];
            #pragma unroll
            for (int j = 0; j < 8; ++j)
                v[j] = W[(size_t)(s * 32 + g * 8 + j) * 64 + nf * 16 + lc];
            short8 hi;
            #pragma unroll
            for (int j = 0; j < 8; ++j) hi[j] = (short)f32_bf16_rn(v[j]);
            hf[(size_t)((hsrc * 2 + s) * 4 + nf) * 64 + lane] = hi;
        }
    }
}

// ---------------------------------------------------------------------------
// zgemm_mfma v4: all-bf16 features. Z and e_prev consumed directly as bf16
// fragments (no splits); bot chunks use W hi+lo (2 products).
// ---------------------------------------------------------------------------
__launch_bounds__(512)
__global__ void zgemm_mfma(const ushort_t* __restrict__ Zb16,
                           const ushort_t* __restrict__ EbPrev,
                           const short8* __restrict__ wf,
                           const float* __restrict__ relb,
                           const float* __restrict__ S,
                           ushort_t* __restrict__ Enb, int M)
{
    __shared__ short8 wlds[2][1024];   // 2 x 16 KB

    const int t = threadIdx.x;
    const int wid = t >> 6, lane = t & 63;
    const int lc = lane & 15, lg = lane >> 4;
    const int row0 = blockIdx.x * 128 + wid * 16;

    const int nA = row0 + lc;
    const bool okA = (nA < M);
    const int nodeA = okA ? nA : 0;

    const int sq = t >> 6, sl = t & 63;
    const int wrA = (sq * 2 + 0) * 64 + sl;
    const int wrB = (sq * 2 + 1) * 64 + sl;

    // e_prev frags (bf16 direct)
    short8 eh[2];
    #pragma unroll
    for (int s = 0; s < 2; ++s) {
        const ushort_t* p = &EbPrev[(size_t)nodeA * 64 + s * 32 + lg * 8];
        eh[s] = okA ? *(const short8*)p : zero8();
    }

    float sD[4][RREL];
    #pragma unroll
    for (int i = 0; i < 4; ++i) {
        int nd = row0 + lg * 4 + i;
        int ns = (nd < M) ? nd : 0;
        #pragma unroll
        for (int r = 0; r < RREL; ++r)
            sD[i][r] = S[(size_t)ns * RREL + r];
    }

    {
        const short8* wp = wf + (size_t)t * 2;
        short8 sa = wp[0], sb = wp[1];
        wlds[0][wrA] = sa; wlds[0][wrB] = sb;
    }
    short8 az0, az1;
    {
        const ushort_t* zb = &Zb16[(size_t)nodeA * 320 + lg * 8];
        az0 = okA ? *(const short8*)(zb)      : zero8();
        az1 = okA ? *(const short8*)(zb + 32) : zero8();
    }
    __syncthreads();

    f32x4 acc[4];
    #pragma unroll
    for (int nf = 0; nf < 4; ++nf) acc[nf] = (f32x4){0.f, 0.f, 0.f, 0.f};

    short8 sreg_a, sreg_b;
    short8 pz0, pz1;

    #pragma unroll
    for (int c = 0; c < 10; ++c) {
        const int cb = c & 1;
        if (c < 9) {
            const short8* wp = wf + (size_t)(c + 1) * 1024 + (size_t)t * 2;
            sreg_a = wp[0]; sreg_b = wp[1];
        }
        if (c < 4) {
            const ushort_t* zb = &Zb16[(size_t)nodeA * 320 + (c + 1) * 64 + lg * 8];
            pz0 = okA ? *(const short8*)(zb)      : zero8();
            pz1 = okA ? *(const short8*)(zb + 32) : zero8();
        }

        if (c < 5) {
            #pragma unroll
            for (int s = 0; s < 2; ++s) {
                short8 Az = (s == 0) ? az0 : az1;
                #pragma unroll
                for (int nf = 0; nf < 4; ++nf) {
                    short8 bh = wlds[cb][((s * 4 + nf) * 2 + 0) * 64 + lane];
                    short8 bl = wlds[cb][((s * 4 + nf) * 2 + 1) * 64 + lane];
                    acc[nf] = __builtin_amdgcn_mfma_f32_16x16x32_bf16(Az, bh, acc[nf], 0, 0, 0);
                    acc[nf] = __builtin_amdgcn_mfma_f32_16x16x32_bf16(Az, bl, acc[nf], 0, 0, 0);
                }
            }
        } else {
            f32x4 tmp[4];
            #pragma unroll
            for (int nf = 0; nf < 4; ++nf) tmp[nf] = (f32x4){0.f, 0.f, 0.f, 0.f};
            #pragma unroll
            for (int s = 0; s < 2; ++s)
                #pragma unroll
                for (int nf = 0; nf < 4; ++nf) {
                    short8 bh = wlds[cb][((s * 4 + nf) * 2 + 0) * 64 + lane];
                    short8 bl = wlds[cb][((s * 4 + nf) * 2 + 1) * 64 + lane];
                    tmp[nf] = __builtin_amdgcn_mfma_f32_16x16x32_bf16(eh[s], bh, tmp[nf], 0, 0, 0);
                    tmp[nf] = __builtin_amdgcn_mfma_f32_16x16x32_bf16(eh[s], bl, tmp[nf], 0, 0, 0);
                }
            const int r = c - 5;
            #pragma unroll
            for (int nf = 0; nf < 4; ++nf)
                #pragma unroll
                for (int i = 0; i < 4; ++i)
                    acc[nf][i] += sD[i][r] * tmp[nf][i];
        }

        if (c < 4) { az0 = pz0; az1 = pz1; }

        if (c < 9) {
            __syncthreads();
            wlds[cb ^ 1][wrA] = sreg_a;
            wlds[cb ^ 1][wrB] = sreg_b;
            __syncthreads();
        }
    }

    float bbv[4][RREL];
    #pragma unroll
    for (int nf = 0; nf < 4; ++nf)
        #pragma unroll
        for (int r = 0; r < RREL; ++r)
            bbv[nf][r] = relb[r * 64 + nf * 16 + lc];

    #pragma unroll
    for (int i = 0; i < 4; ++i) {
        int nd = row0 + lg * 4 + i;
        if (nd >= M) continue;
        #pragma unroll
        for (int nf = 0; nf < 4; ++nf) {
            float v = acc[nf][i];
            #pragma unroll
            for (int r = 0; r < RREL; ++r)
                v += sD[i][r] * bbv[nf][r];
            Enb[(size_t)nd * 64 + nf * 16 + lc] = f32_bf16_rn(v);
        }
    }
}

// ---------------------------------------------------------------------------
// CSR build over (dst,type) keys
// ---------------------------------------------------------------------------
__launch_bounds__(256)
__global__ void deg5_hist(const int* __restrict__ dst, const int* __restrict__ etype,
                          int* __restrict__ deg5, int* __restrict__ slot5)
{
    int e = blockIdx.x * 256 + threadIdx.x;
    if (e < NE) slot5[e] = atomicAdd(&deg5[dst[e] * RREL + etype[e]], 1);
}

__launch_bounds__(256)
__global__ void b1_reduce(const int* __restrict__ deg5, int* __restrict__ b1)
{
    __shared__ int sh[256];
    int i = blockIdx.x * 256 + threadIdx.x;
    sh[threadIdx.x] = (i < NR) ? deg5[i] : 0;
    __syncthreads();
    for (int s = 128; s > 0; s >>= 1) {
        if (threadIdx.x < s) sh[threadIdx.x] += sh[threadIdx.x + s];
        __syncthreads();
    }
    if (threadIdx.x == 0) b1[blockIdx.x] = sh[0];
}

__launch_bounds__(256)
__global__ void scan_seq(int* __restrict__ b1, int n)
{
    __shared__ int sh[256];
    __shared__ int carry;
    if (threadIdx.x == 0) carry = 0;
    __syncthreads();
    for (int base = 0; base < n; base += 256) {
        int i = base + threadIdx.x;
        int v = (i < n) ? b1[i] : 0;
        sh[threadIdx.x] = v;
        __syncthreads();
        for (int off = 1; off < 256; off <<= 1) {
            int x = (threadIdx.x >= off) ? sh[threadIdx.x - off] : 0;
            __syncthreads();
            sh[threadIdx.x] += x;
            __syncthreads();
        }
        int excl = sh[threadIdx.x] - v + carry;
        if (i < n) b1[i] = excl;
        __syncthreads();
        if (threadIdx.x == 255) carry = excl + v;
        __syncthreads();
    }
}

__launch_bounds__(256)
__global__ void offs5_final(const int* __restrict__ deg5, const int* __restrict__ b1,
                            int* __restrict__ offs5)
{
    __shared__ int sh[256];
    int t = threadIdx.x;
    int i = blockIdx.x * 256 + t;
    int v = (i < NR) ? deg5[i] : 0;
    sh[t] = v;
    __syncthreads();
    for (int off = 1; off < 256; off <<= 1) {
        int x = (t >= off) ? sh[t - off] : 0;
        __syncthreads();
        sh[t] += x;
        __syncthreads();
    }
    int excl = sh[t] - v + b1[blockIdx.x];
    if (i <= NR) offs5[i] = excl;
}

// scatter: epack[offs5[dst*5+r] + slot5[e]] = {w, src} packed u64
__launch_bounds__(256)
__global__ void scatter_pass(const int* __restrict__ src, const int* __restrict__ dst,
                             const int* __restrict__ etype,
                             const float* __restrict__ etime,
                             const float* __restrict__ beta,
                             const float* __restrict__ lambda_p,
                             const int* __restrict__ slot5, const int* __restrict__ offs5,
                             unsigned long long* __restrict__ epack)
{
    int e = blockIdx.x * 256 + threadIdx.x;
    if (e >= NE) return;
    float b[12];
    #pragma unroll
    for (int j = 0; j < 12; ++j) b[j] = beta[j];
    const float* et = etime + (size_t)e * 12;
    float4 v0 = *(const float4*)(et);
    float4 v1 = *(const float4*)(et + 4);
    float4 v2 = *(const float4*)(et + 8);
    float logit = v0.x*b[0] + v0.y*b[1] + v0.z*b[2] + v0.w*b[3]
                + v1.x*b[4] + v1.y*b[5] + v1.z*b[6] + v1.w*b[7]
                + v2.x*b[8] + v2.y*b[9] + v2.z*b[10] + v2.w*b[11];
    float we = lambda_p[0] * expf(-logit);
    int p = offs5[dst[e] * RREL + etype[e]] + slot5[e];
    epack[p] = ((unsigned long long)__float_as_uint(we) << 32) | (unsigned)src[e];
}

// ---------------------------------------------------------------------------
extern "C" void kernel_launch(void* const* d_in, const int* in_sizes, int n_in,
                              void* d_out, int out_size, void* d_ws, size_t ws_size,
                              hipStream_t stream)
{
    const float* x        = (const float*)d_in[0];
    const int*   eidx     = (const int*)d_in[1];
    const int*   etype    = (const int*)d_in[2];
    const float* etime    = (const float*)d_in[3];
    const float* lambda_p = (const float*)d_in[4];
    const float* beta     = (const float*)d_in[5];
    const float* field_W  = (const float*)d_in[6];
    const float* field_b  = (const float*)d_in[7];
    const float* rel1_W   = (const float*)d_in[8];
    const float* rel1_b   = (const float*)d_in[9];
    const float* rel2_W   = (const float*)d_in[10];
    const float* rel2_b   = (const float*)d_in[11];
    const float* out0_W   = (const float*)d_in[12];
    const float* out0_b   = (const float*)d_in[13];
    const float* out1_W   = (const float*)d_in[14];
    const float* out1_b   = (const float*)d_in[15];
    const float* out2_W   = (const float*)d_in[16];
    const float* out2_b   = (const float*)d_in[17];
    const int* src = eidx;
    const int* dst = eidx + NE;
    float* out = (float*)d_out;

    char* wsb = (char*)d_ws;
    size_t off = 0;
    auto carve = [&](size_t bytes) -> void* {
        void* p = (void*)(wsb + off);
        off += (bytes + 255) & ~(size_t)255;
        return p;
    };
    int*   deg5   = (int*)carve((size_t)NR * 4);            // 1 MB
    int*   offs5  = (int*)carve((size_t)(NR + 1) * 4);      // 1 MB
    int*   b1     = (int*)carve((size_t)NB5 * 4);
    int*   slot5  = (int*)carve((size_t)NE * 4);            // 3.2 MB
    float* S      = (float*)carve((size_t)NR * 4);          // 1 MB
    unsigned long long* epack = (unsigned long long*)carve((size_t)NE * 8); // 6.4 MB
    ushort_t* e0b = (ushort_t*)carve((size_t)NN * 64 * 2);  // 6.4 MB bf16
    ushort_t* e1b = (ushort_t*)carve((size_t)NN * 64 * 2);  // 6.4 MB bf16
    ushort_t* e2b = (ushort_t*)carve((size_t)NN * 64 * 2);  // 6.4 MB bf16
    ushort_t* Zb16 = (ushort_t*)carve((size_t)NN * 320 * 2); // 32 MB bf16 Z
    short8* wf1   = (short8*)carve((size_t)20 * 16384);     // 320 KB
    short8* wf2   = (short8*)carve((size_t)20 * 16384);     // 320 KB
    short8* ff    = (short8*)carve((size_t)16 * 64 * 16);   // 16 KB field frags
    short8* hf    = (short8*)carve((size_t)24 * 64 * 16);   // 24 KB head frags

    dim3 blk(256);
    const int NT128 = (NN + 127) / 128;     // 391
    const int EB = (NE + 255) / 256;
    const int GB = (NN * 64 + 255) / 256;   // one wave per node

    // ---- CSR build over (dst,type) + weight frag prep ----
    zero_deg5<<<256, blk, 0, stream>>>((int4*)deg5, (NR + 3) / 4);
    deg5_hist<<<EB, blk, 0, stream>>>(dst, etype, deg5, slot5);
    prep_wfrag<<<27, blk, 0, stream>>>(rel1_W, rel2_W, field_W, out0_W, out1_W, out2_W,
                                       wf1, wf2, ff, hf);
    b1_reduce<<<NB5, blk, 0, stream>>>(deg5, b1);
    scan_seq<<<1, blk, 0, stream>>>(b1, NB5);
    offs5_final<<<NB5, blk, 0, stream>>>(deg5, b1, offs5);
    scatter_pass<<<EB, blk, 0, stream>>>(src, dst, etype, etime, beta, lambda_p,
                                         slot5, offs5, epack);

    // ---- e0b = bf16(x @ field_W + field_b) ----
    lin_mfma<<<dim3(NT128), dim3(512), 0, stream>>>(x, ff, field_b, e0b, NN);

    // ---- layer 1 ----
    zgather<<<GB, blk, 0, stream>>>(offs5, epack, e0b, Zb16, S);
    zgemm_mfma<<<dim3(NT128), dim3(512), 0, stream>>>(Zb16, e0b, wf1, rel1_b, S, e1b, NN);

    // ---- layer 2 ----
    zgather<<<GB, blk, 0, stream>>>(offs5, epack, e1b, Zb16, S);
    zgemm_mfma<<<dim3(NT128), dim3(512), 0, stream>>>(Zb16, e1b, wf2, rel2_b, S, e2b, NN);

    // ---- output head (bf16 features, single pass) ----
    head_mfma<<<dim3(NT128), dim3(512), 0, stream>>>(e0b, e1b, e2b, hf,
                                                     out0_b, out1_b, out2_b, out, NN);
}